// Round 13
// baseline (851.817 us; speedup 1.0000x reference)
//
#include <hip/hip_runtime.h>

typedef short s8v __attribute__((ext_vector_type(8)));
typedef float f4v __attribute__((ext_vector_type(4)));
typedef unsigned short bfu;

#define MFMA16 __builtin_amdgcn_mfma_f32_16x16x32_bf16

constexpr int kSEQ = 4096;
constexpr int kBL  = 8192;   // BATCH*SEQLEN
constexpr int kDM  = 2048;   // D_MODEL
constexpr int kDP  = 8352;   // D_IN_PROJ
constexpr int kDPpad = 8448; // padded to 66*128
constexpr int kDI  = 4096;   // D_INNER
constexpr int kCV  = 4224;   // CONV_DIM
constexpr int kXBC = 4256;   // CONV_DIM + NHEADS (xBC | dt columns)
constexpr int kNH  = 32;
constexpr int kHD  = 128;
constexpr int kDS  = 64;
constexpr int kCH  = 256;    // CHUNK
constexpr int kLDW = 2112;   // winT row stride (breaks 4 KB power-of-2 alias)
constexpr int kLDY = 4160;   // y16 row stride (breaks 8 KB power-of-2 alias)

#if defined(__has_builtin)
#  if __has_builtin(__builtin_amdgcn_global_load_lds)
#    define HAS_GLD 1
#  endif
#endif
#ifndef HAS_GLD
#  define HAS_GLD 0
#endif

// Async 16B global->LDS. LDS dest is wave-uniform base + lane*16 (linear).
__device__ __forceinline__ void gld_lds16(const void* g, void* lbase, int lane){
#if HAS_GLD
  (void)lane;
  __builtin_amdgcn_global_load_lds(
      (const __attribute__((address_space(1))) void*)g,
      (__attribute__((address_space(3))) void*)lbase, 16, 0, 0);
#else
  *(uint4*)((char*)lbase + lane * 16) = *(const uint4*)g;
#endif
}

__device__ __forceinline__ bfu f2bf(float f){
  union { float f; unsigned u; } c; c.f = f;
  return (bfu)((c.u + 0x7fffu + ((c.u >> 16) & 1u)) >> 16);
}
__device__ __forceinline__ float bf2f(bfu s){
  union { unsigned u; float f; } c; c.u = ((unsigned)s) << 16;
  return c.f;
}

// Tiles are [R rows][64 bf16] = [R][8 slots of 16B], slot XOR-swizzled by (row&7).
__device__ __forceinline__ s8v frag_ld(const char* lds, int rowbase, int kh, int lane){
  int r = rowbase + (lane & 15);
  int slot = (kh << 2) + (lane >> 4);
  return *(const s8v*)(lds + (((r << 3) + (slot ^ (r & 7))) << 4));
}

// ---------------- zero fill (bf16 elements) ----------------
__global__ __launch_bounds__(256) void k_zero(bfu* __restrict__ p, int n){
  int i = blockIdx.x * 256 + threadIdx.x;
  if (i < n) p[i] = 0;
}

// ---------------- fp32 -> bf16 convert ----------------
__global__ __launch_bounds__(256) void k_cvt(const float* __restrict__ s, bfu* __restrict__ d, int n8){
  int i = blockIdx.x * 256 + threadIdx.x;
  int stride = gridDim.x * 256;
  for (; i < n8; i += stride){
    const float4* sp = (const float4*)(s + (size_t)i * 8);
    float4 a = sp[0], b = sp[1];
    uint4 pk; bfu* pp = (bfu*)&pk;
    pp[0]=f2bf(a.x); pp[1]=f2bf(a.y); pp[2]=f2bf(a.z); pp[3]=f2bf(a.w);
    pp[4]=f2bf(b.x); pp[5]=f2bf(b.y); pp[6]=f2bf(b.z); pp[7]=f2bf(b.w);
    *(uint4*)(d + (size_t)i * 8) = pk;
  }
}

// ---------------- fp32 [R][C] -> bf16 [C][R] transpose (dst ld = ldo), optional scale ----------------
__global__ __launch_bounds__(256) void k_transpose(const float* __restrict__ src, bfu* __restrict__ dst,
                                                   int R, int C, const float* __restrict__ scale, int ldo){
  __shared__ float tile[32][33];
  int c0 = blockIdx.x * 32, r0 = blockIdx.y * 32;
  int tx = threadIdx.x, ty = threadIdx.y;
  #pragma unroll
  for (int i = ty; i < 32; i += 8){
    int r = r0 + i, cc = c0 + tx;
    tile[i][tx] = (r < R && cc < C) ? src[(size_t)r * C + cc] : 0.f;
  }
  __syncthreads();
  #pragma unroll
  for (int i = ty; i < 32; i += 8){
    int dr = c0 + i, dc = r0 + tx;
    if (dr < C && dc < R){
      float v = tile[tx][i];
      if (scale) v *= scale[dc];
      dst[(size_t)dr * ldo + dc] = f2bf(v);
    }
  }
}

// ============ 256x128 GEMM, 2-blocks/CU (BK=32, 2 LDS bufs of 24 KB) ============
// out[M][N] = A[M][K] * Bt[N][K]^T, bf16 in, fp32 acc. A rows stride lda, Bt rows ldb.
// MODE 0: fp32 output (ldc = N), scaled per-row by rsv[]. MODE 2: bf16 split z/xbc.
// 8 waves (4 row x 2 col), wave tile 64x64 (acc = 64 regs -> <=128 total ->
// 2 blocks/CU at 48 KB LDS). The exposed vmcnt(0) drain per tile is hidden by
// the co-resident block (m114 cross-block overlap) -- the mechanism every
// 1-block/CU 256^2 schedule lacked.
// Band supertiles: 8 bands of 4 tm-rows x all tn; cpx == band size so each XCD
// owns one band (A slice 4 MB, L2-resident; B panel re-reads adjacent).
// Granule involution (r9-verified): LDS granule g (row=g>>2, c=g&3) holds
// source chunk c ^ ((row>>1)&3); frag read chunk = (lane>>4) ^ ((lane>>1)&3).
template<int MODE>
__global__ __launch_bounds__(512, 4) void k_gemm256(const bfu* __restrict__ A, const bfu* __restrict__ Bt,
                                                    float* __restrict__ outF, bfu* __restrict__ outZ,
                                                    bfu* __restrict__ outX, const float* __restrict__ rsv,
                                                    int tilesN, int N, int K, int lda, int ldb){
  extern __shared__ char lds[];         // 49152 B: 2 bufs x (A 16KB + B 8KB)
  int t = threadIdx.x, lane = t & 63, wave = t >> 6;
  int wr = wave >> 1, wc = wave & 1;    // 4 row-groups x 2 col-groups
  // bijective XCD swizzle (gridDim.x % 8 == 0 by construction)
  int nwg = gridDim.x;
  int bid = blockIdx.x;
  int cpx = nwg >> 3;
  int wg = (bid & 7) * cpx + (bid >> 3);
  // band-supertile mapping: tilesM % 4 == 0 for both call sites
  int bandSz = tilesN << 2;
  int band = wg / bandSz;
  int rem  = wg - band * bandSz;
  int tnTile = rem >> 2;
  int tmTile = (band << 2) + (rem & 3);
  int tm = tmTile << 8, tn = tnTile << 7;
  const bfu* Ab = A + (size_t)tm * lda;
  const bfu* Bb = Bt + (size_t)tn * ldb;

  // stage one 128-row x 32-col half (1 gld/thread): granule t -> row t>>2,
  // source chunk (t&3) ^ ((t>>3)&3)  [involution]
  int sr = t >> 2, scc = (t & 3) ^ ((t >> 3) & 3);
  auto stage_half = [&](const bfu* src, int ld, int ldsOfs, int kcol0){
    gld_lds16(src + (size_t)sr * ld + kcol0 + scc * 8,
              lds + ldsOfs + (wave << 10), lane);
  };
  // frag read swizzle: row-part collapses (frag row bases are multiples of 16)
  int swz = ((lane >> 4) ^ ((lane >> 1) & 3)) << 4;

  f4v acc[4][4];
  f4v zz = {0.f, 0.f, 0.f, 0.f};
  #pragma unroll
  for (int m = 0; m < 4; ++m)
    #pragma unroll
    for (int n = 0; n < 4; ++n) acc[m][n] = zz;

  int nt = K >> 5;
  // prologue: stage tile 0 (A 2 halves + B 1 half); drain; barrier
  stage_half(Ab, lda, 0, 0);
  stage_half(Ab + (size_t)128 * lda, lda, 8192, 0);
  stage_half(Bb, ldb, 16384, 0);
  __builtin_amdgcn_sched_barrier(0);
  asm volatile("s_waitcnt vmcnt(0)" ::: "memory");
  __builtin_amdgcn_sched_barrier(0);
  __builtin_amdgcn_s_barrier();
  __builtin_amdgcn_sched_barrier(0);

  #pragma unroll 1
  for (int tt = 0; tt < nt; ++tt){
    int cb = (tt & 1) * 24576;
    bool more = (tt + 1 < nt);
    if (more){
      int nb = ((tt + 1) & 1) * 24576;
      int kc = (tt + 1) << 5;
      stage_half(Ab, lda, nb, kc);
      stage_half(Ab + (size_t)128 * lda, lda, nb + 8192, kc);
      stage_half(Bb, ldb, nb + 16384, kc);
    }
    s8v af[4], bf[4];
    #pragma unroll
    for (int m = 0; m < 4; ++m)
      af[m] = *(const s8v*)(lds + cb + ((wr * 64 + m * 16 + (lane & 15)) << 6) + swz);
    #pragma unroll
    for (int n = 0; n < 4; ++n)
      bf[n] = *(const s8v*)(lds + cb + 16384 + ((wc * 64 + n * 16 + (lane & 15)) << 6) + swz);
    __builtin_amdgcn_s_setprio(1);
    #pragma unroll
    for (int n = 0; n < 4; ++n)
      #pragma unroll
      for (int m = 0; m < 4; ++m)
        acc[m][n] = MFMA16(af[m], bf[n], acc[m][n], 0, 0, 0);
    __builtin_amdgcn_s_setprio(0);
    __builtin_amdgcn_sched_barrier(0);
    asm volatile("s_waitcnt vmcnt(0)" ::: "memory");
    __builtin_amdgcn_sched_barrier(0);
    __builtin_amdgcn_s_barrier();
    __builtin_amdgcn_sched_barrier(0);
  }

  int r0 = (lane >> 4) << 2;
  if (MODE == 0){
    // stage per-row rs factors in LDS (staging region dead after final drain)
    float* rsl = (float*)lds;
    if (t < 256) rsl[t] = rsv[tm + t];
    __syncthreads();
    #pragma unroll
    for (int m = 0; m < 4; ++m)
      #pragma unroll
      for (int n = 0; n < 4; ++n)
        #pragma unroll
        for (int r = 0; r < 4; ++r){
          int rl = wr * 64 + m * 16 + r0 + r;
          size_t rg = (size_t)(tm + rl);
          int cg = tn + wc * 64 + n * 16 + (lane & 15);
          outF[rg * N + cg] = acc[m][n][r] * rsl[rl];
        }
  } else {
    // bf16 epilogue: restage C (256x128) in two 128-row halves of 32 KB
    bfu* op; int ldo, cofs;
    if (tn < 4096){ op = outZ; ldo = 4096; cofs = 0; }
    else          { op = outX; ldo = kXBC; cofs = 4096; }
    #pragma unroll
    for (int h = 0; h < 2; ++h){
      __syncthreads();
      if ((wr >> 1) == h){
        #pragma unroll
        for (int m = 0; m < 4; ++m)
          #pragma unroll
          for (int n = 0; n < 4; ++n){
            int col = wc * 64 + n * 16 + (lane & 15);
            int cs = col >> 3, cl = col & 7;
            #pragma unroll
            for (int r = 0; r < 4; ++r){
              int row = (wr & 1) * 64 + m * 16 + r0 + r;   // local 0..127
              *(bfu*)(lds + row * 256 + ((cs ^ (row & 7)) << 4) + cl * 2) = f2bf(acc[m][n][r]);
            }
          }
      }
      __syncthreads();
      int row = t >> 2;                  // 0..127
      bfu* baseo = op + (size_t)(tm + h * 128 + row) * ldo + (tn - cofs);
      #pragma unroll
      for (int i = 0; i < 4; ++i){
        int g = (t & 3) * 4 + i;         // 16 granules of 16B per 256B row
        int cg = tn + g * 8;
        if (cg < kDP){
          uint4 v = *(const uint4*)(lds + row * 256 + ((g ^ (row & 7)) << 4));
          *(uint4*)(baseo + g * 8) = v;
        }
      }
    }
  }
}

// ---------------- causal depthwise conv4 + bias + SiLU; emits xT, B, BT, C ----------------
__global__ __launch_bounds__(256) void k_conv(const bfu* __restrict__ xbc, const float* __restrict__ cw,
    const float* __restrict__ cb, bfu* __restrict__ xT,
    bfu* __restrict__ B16o, bfu* __restrict__ BTo, bfu* __restrict__ C16o){
  int cht = blockIdx.x;                 // 0..65 channel tile (over CONV_DIM)
  int lt = blockIdx.y;                  // 0..127 seq tile over b*l
  int b = lt >> 6;
  int l0 = (lt & 63) << 6;
  int t = threadIdx.x;
  __shared__ float w[256];
  __shared__ float bias[64];
  __shared__ bfu in16[67][66];
  __shared__ bfu out16[64][66];
  if (t < 64) bias[t] = cb[cht * 64 + t];
  w[t] = cw[cht * 256 + t];
  int chbase = cht * 64;
  for (int i = t; i < 67 * 64; i += 256){
    int rrow = i >> 6, cc = i & 63;
    int l = l0 + rrow - 3;
    bfu hv = 0;
    if (l >= 0) hv = xbc[((size_t)b * kSEQ + l) * kXBC + chbase + cc];
    in16[rrow][cc] = hv;
  }
  __syncthreads();
  for (int i = t; i < 4096; i += 256){
    int lr = i >> 6, cc = i & 63;
    float acc = bias[cc];
    #pragma unroll
    for (int j = 0; j < 4; ++j)
      acc += bf2f(in16[lr + j][cc]) * w[cc * 4 + j];
    float sv = acc / (1.f + __expf(-acc));
    out16[lr][cc] = f2bf(sv);
  }
  __syncthreads();
  // row-major outputs: B and C only
  if (chbase >= 4096){
    for (int i = t; i < 4096; i += 256){
      int lr = i >> 6, cc = i & 63;
      size_t row = (size_t)b * kSEQ + l0 + lr;
      int ch = chbase + cc;
      bfu v = out16[lr][cc];
      if (ch < 4096 + kDS) B16o[row * kDS + (ch - 4096)] = v;
      else                 C16o[row * kDS + (ch - 4096 - kDS)] = v;
    }
  }
  // transposed outputs: x -> xT, B -> BT
  if (chbase < 4096 + kDS){
    for (int i = t; i < 4096; i += 256){
      int cc = i >> 6, lr = i & 63;
      int ch = chbase + cc;
      int lg = l0 + lr;
      bfu v = out16[lr][cc];
      if (ch < 4096){
        int hh = ch >> 7, p = ch & 127;
        xT[(((size_t)b * kNH + hh) * kHD + p) * kSEQ + lg] = v;
      } else if (ch < 4096 + kDS){
        BTo[((size_t)b * kDS + (ch - 4096)) * kSEQ + lg] = v;
      }
    }
  }
}

// ---------------- dt = softplus(raw + bias); dA = -exp(A_log)*dt; per-chunk inclusive cumsum ----------------
__global__ __launch_bounds__(256) void k_dtscan(const bfu* __restrict__ xbc, const float* __restrict__ dt_bias,
    const float* __restrict__ A_log, float* __restrict__ dtf, float* __restrict__ acum){
  int bi = blockIdx.x;                  // ((b*16+c)*32+h)
  int h = bi & 31, c = (bi >> 5) & 15, b = bi >> 9;
  int t = threadIdx.x;
  size_t row = (size_t)b * kSEQ + c * kCH + t;
  float draw = bf2f(xbc[row * kXBC + kCV + h]) + dt_bias[h];
  float dt = (draw > 20.f) ? draw : log1pf(__expf(draw));
  dtf[row * kNH + h] = dt;
  float dA = -__expf(A_log[h]) * dt;
  __shared__ float s[256];
  s[t] = dA;
  __syncthreads();
  #pragma unroll
  for (int off = 1; off < 256; off <<= 1){
    float v = (t >= off) ? s[t - off] : 0.f;
    __syncthreads();
    s[t] += v;
    __syncthreads();
  }
  acum[(size_t)bi * 256 + t] = s[t];
}

// ---------------- per-chunk local states[p][n] = sum_l Xt[p][l] * B[l][n]*dt[l]*exp(Atot-Acum[l]) ----------------
__global__ __launch_bounds__(256) void k_states(const bfu* __restrict__ xT, const bfu* __restrict__ BT,
    const float* __restrict__ dtf, const float* __restrict__ acum, bfu* __restrict__ states){
  int bi = blockIdx.x;
  int h = bi & 31, c = (bi >> 5) & 15, b = bi >> 9;
  int t = threadIdx.x, lane = t & 63, wave = t >> 6;
  int wr = wave >> 1, wc = wave & 1;
  __shared__ uint4 ldsX4[1024];         // [128 p][64 l] bf16
  __shared__ uint4 ldsB4[512];          // [64 n][64 l] bf16 (scaled)
  __shared__ float dsv[256];
  char* ldsX = (char*)ldsX4;
  char* ldsB = (char*)ldsB4;
  float Atot = acum[(size_t)bi * 256 + 255];
  {
    size_t row = (size_t)b * kSEQ + c * kCH + t;
    dsv[t] = dtf[row * kNH + h] * __expf(Atot - acum[(size_t)bi * 256 + t]);
  }
  f4v zz = {0.f, 0.f, 0.f, 0.f};
  f4v acc[4][2];
  #pragma unroll
  for (int m = 0; m < 4; ++m){ acc[m][0] = zz; acc[m][1] = zz; }
  const bfu* xTp = xT + ((size_t)b * kNH + h) * kHD * kSEQ + c * kCH;
  const bfu* BTp = BT + (size_t)b * kDS * kSEQ + c * kCH;
  __syncthreads();
  for (int kb = 0; kb < 4; ++kb){
    #pragma unroll
    for (int it = 0; it < 4; ++it){
      int s = it * 256 + t;
      int row = s >> 3;
      int srcslot = (s & 7) ^ (row & 7);
      gld_lds16(xTp + (size_t)row * kSEQ + kb * 64 + srcslot * 8,
                ldsX + it * 4096 + wave * 1024, lane);
    }
    #pragma unroll
    for (int it = 0; it < 2; ++it){
      int cidx = it * 256 + t;
      int row = cidx >> 3, slot = cidx & 7;
      uint4 v = *(const uint4*)(BTp + (size_t)row * kSEQ + kb * 64 + slot * 8);
      bfu* hp = (bfu*)&v;
      #pragma unroll
      for (int j = 0; j < 8; ++j)
        hp[j] = f2bf(bf2f(hp[j]) * dsv[kb * 64 + slot * 8 + j]);
      *(uint4*)(ldsB + (((row << 3) + (slot ^ (row & 7))) << 4)) = v;
    }
    __syncthreads();
    s8v af[4][2], bb[2][2];
    #pragma unroll
    for (int m = 0; m < 4; ++m){
      af[m][0] = frag_ld(ldsX, wr * 64 + m * 16, 0, lane);
      af[m][1] = frag_ld(ldsX, wr * 64 + m * 16, 1, lane);
    }
    #pragma unroll
    for (int nf = 0; nf < 2; ++nf){
      bb[nf][0] = frag_ld(ldsB, wc * 32 + nf * 16, 0, lane);
      bb[nf][1] = frag_ld(ldsB, wc * 32 + nf * 16, 1, lane);
    }
    #pragma unroll
    for (int kh = 0; kh < 2; ++kh)
      #pragma unroll
      for (int m = 0; m < 4; ++m)
        #pragma unroll
        for (int nf = 0; nf < 2; ++nf)
          acc[m][nf] = MFMA16(af[m][kh], bb[nf][kh], acc[m][nf], 0, 0, 0);
    __syncthreads();
  }
  bfu* sp = states + (size_t)bi * 8192;
  int r0 = (lane >> 4) << 2;
  #pragma unroll
  for (int m = 0; m < 4; ++m)
    #pragma unroll
    for (int nf = 0; nf < 2; ++nf)
      #pragma unroll
      for (int r = 0; r < 4; ++r){
        int p = wr * 64 + m * 16 + r0 + r;
        int n = wc * 32 + nf * 16 + (lane & 15);
        sp[p * 64 + n] = f2bf(acc[m][nf][r]);
      }
}

// ---------------- inter-chunk state recurrence (in-place; split over 4 j-groups) ----------------
__global__ __launch_bounds__(256) void k_scan(bfu* __restrict__ st, const float* __restrict__ acum){
  int bh = blockIdx.x >> 2;             // 0..63  (b*32+h)
  int jg = blockIdx.x & 3;              // 0..3
  int b = bh >> 5, h = bh & 31;
  int t = threadIdx.x;
  float run[8];
  #pragma unroll
  for (int j = 0; j < 8; ++j) run[j] = 0.f;
  for (int c = 0; c < 16; ++c){
    size_t bi = (size_t)((b * 16 + c) * 32 + h);
    float eT = __expf(acum[bi * 256 + 255]);
    size_t base = bi * 8192 + (size_t)jg * 2048;
    #pragma unroll
    for (int j = 0; j < 8; ++j){
      size_t idx = base + j * 256 + t;
      float sl = bf2f(st[idx]);
      st[idx] = f2bf(run[j]);
      run[j] = run[j] * eT + sl;
    }
  }
}

// ---------------- Y = (P + D*I)X + Y_off, * silu(z) -> y16 (bf16, [BL][kLDY]) ----------------
__global__ __launch_bounds__(256) void k_y(
    const bfu* __restrict__ xT, const bfu* __restrict__ Bm, const bfu* __restrict__ Cm,
    const bfu* __restrict__ SIs, const float* __restrict__ dtf, const float* __restrict__ acum,
    const bfu* __restrict__ z16, const float* __restrict__ Dp,
    bfu* __restrict__ y16)
{
  int bi = blockIdx.x;
  int h = bi & 31, c = (bi >> 5) & 15, b = bi >> 9;
  int ph = blockIdx.y;                  // p half (64 cols)
  int t = threadIdx.x, lane = t & 63, wave = t >> 6;
  int wl = wave << 6;                   // wave's 64 rows of the chunk
  __shared__ uint4 ldsP4[2048];         // per-wave P [64][64] bf16, 4x8KB; reused as Y restage
  __shared__ uint4 ldsT4[512];          // SI tile then Xt tiles [64][64] bf16
  __shared__ float acumS[256];
  __shared__ float dtS[256];
  char* ldsP = ((char*)ldsP4) + (wave << 13);
  char* ldsT = (char*)ldsT4;
  size_t rowbase = (size_t)b * kSEQ + c * kCH;
  acumS[t] = acum[(size_t)bi * 256 + t];
  dtS[t] = dtf[(rowbase + t) * kNH + h];
  const bfu* SIp = SIs + (size_t)bi * 8192 + (size_t)ph * 4096;  // [64 p][64 n] bf16
  #pragma unroll
  for (int it = 0; it < 2; ++it){
    int cidx = it * 256 + t;
    int row = cidx >> 3, slot = cidx & 7;
    uint4 v = *(const uint4*)(SIp + row * 64 + slot * 8);
    *(uint4*)(ldsT + (((row << 3) + (slot ^ (row & 7))) << 4)) = v;
  }
  const bfu* Cp = Cm + rowbase * kDS;
  s8v cf[4][2];
  #pragma unroll
  for (int m = 0; m < 4; ++m){
    cf[m][0] = *(const s8v*)(Cp + (size_t)(wl + m * 16 + (lane & 15)) * kDS + ((lane >> 4) << 3));
    cf[m][1] = *(const s8v*)(Cp + (size_t)(wl + m * 16 + (lane & 15)) * kDS + 32 + ((lane >> 4) << 3));
  }
  __syncthreads();
  float Arow[16];
  #pragma unroll
  for (int m = 0; m < 4; ++m)
    #pragma unroll
    for (int r = 0; r < 4; ++r)
      Arow[m * 4 + r] = acumS[wl + m * 16 + ((lane >> 4) << 2) + r];
  f4v acc[4][4];
  {
    s8v bfo[4][2];
    #pragma unroll
    for (int pf = 0; pf < 4; ++pf){
      bfo[pf][0] = frag_ld(ldsT, pf << 4, 0, lane);
      bfo[pf][1] = frag_ld(ldsT, pf << 4, 1, lane);
    }
    f4v zz = {0.f, 0.f, 0.f, 0.f};
    #pragma unroll
    for (int m = 0; m < 4; ++m)
      #pragma unroll
      for (int pf = 0; pf < 4; ++pf){
        f4v v = zz;
        v = MFMA16(cf[m][0], bfo[pf][0], v, 0, 0, 0);
        v = MFMA16(cf[m][1], bfo[pf][1], v, 0, 0, 0);
        #pragma unroll
        for (int r = 0; r < 4; ++r) v[r] *= __expf(Arow[m * 4 + r]);
        acc[m][pf] = v;
      }
  }
  float Dh = Dp[h];
  const bfu* Bp = Bm + rowbase * kDS;
  const bfu* xTp = xT + (((size_t)b * kNH + h) * kHD + ph * 64) * kSEQ + c * kCH;
  #pragma unroll 1
  for (int sb = 0; sb < 4; ++sb){
    __syncthreads();
    #pragma unroll
    for (int it = 0; it < 2; ++it){
      int s = it * 256 + t;
      int row = s >> 3;
      int srcslot = (s & 7) ^ (row & 7);
      gld_lds16(xTp + (size_t)row * kSEQ + sb * 64 + srcslot * 8,
                ldsT + it * 4096 + wave * 1024, lane);
    }
    f4v sv[4][4];
    {
      s8v bsf[4][2];
      #pragma unroll
      for (int sf = 0; sf < 4; ++sf){
        bsf[sf][0] = *(const s8v*)(Bp + (size_t)(sb * 64 + sf * 16 + (lane & 15)) * kDS + ((lane >> 4) << 3));
        bsf[sf][1] = *(const s8v*)(Bp + (size_t)(sb * 64 + sf * 16 + (lane & 15)) * kDS + 32 + ((lane >> 4) << 3));
      }
      f4v zz = {0.f, 0.f, 0.f, 0.f};
      #pragma unroll
      for (int m = 0; m < 4; ++m)
        #pragma unroll
        for (int sf = 0; sf < 4; ++sf){
          f4v v = zz;
          v = MFMA16(cf[m][0], bsf[sf][0], v, 0, 0, 0);
          v = MFMA16(cf[m][1], bsf[sf][1], v, 0, 0, 0);
          sv[m][sf] = v;
        }
    }
    int scb = sb << 6;
    float As[4], dts_[4];
    #pragma unroll
    for (int sf = 0; sf < 4; ++sf){
      As[sf] = acumS[scb + sf * 16 + (lane & 15)];
      dts_[sf] = dtS[scb + sf * 16 + (lane & 15)];
    }
    #pragma unroll
    for (int m = 0; m < 4; ++m)
      #pragma unroll
      for (int sf = 0; sf < 4; ++sf)
        #pragma unroll
        for (int r = 0; r < 4; ++r){
          int rloc = m * 16 + ((lane >> 4) << 2) + r;
          int scl = sf * 16 + (lane & 15);
          int d = (wl + rloc) - (scb + scl);
          float pv = 0.f;
          if (d >= 0)
            pv = sv[m][sf][r] * __expf(Arow[m * 4 + r] - As[sf]) * dts_[sf];
          if (d == 0)
            pv += Dh;                   // D-skip folded into P diagonal
          *(bfu*)(ldsP + rloc * 128 + ((((scl >> 3) ^ (rloc & 7)) << 3) + (scl & 7)) * 2) = f2bf(pv);
        }
    __syncthreads();
    s8v xb[4][2];
    #pragma unroll
    for (int pf = 0; pf < 4; ++pf){
      xb[pf][0] = frag_ld(ldsT, pf << 4, 0, lane);
      xb[pf][1] = frag_ld(ldsT, pf << 4, 1, lane);
    }
    #pragma unroll
    for (int m = 0; m < 4; ++m){
      s8v pa0 = frag_ld(ldsP, m << 4, 0, lane);
      s8v pa1 = frag_ld(ldsP, m << 4, 1, lane);
      #pragma unroll
      for (int pf = 0; pf < 4; ++pf){
        acc[m][pf] = MFMA16(pa0, xb[pf][0], acc[m][pf], 0, 0, 0);
        acc[m][pf] = MFMA16(pa1, xb[pf][1], acc[m][pf], 0, 0, 0);
      }
    }
  }
  // ---- coalesced gated epilogue: restage Y tile [256 rows][64 cols] through LDS ----
  __syncthreads();
  char* ldsY = (char*)ldsP4;            // full 32KB, slot^row&7 swizzled rows of 128B
  #pragma unroll
  for (int m = 0; m < 4; ++m)
    #pragma unroll
    for (int pf = 0; pf < 4; ++pf)
      #pragma unroll
      for (int r = 0; r < 4; ++r){
        int rloc = wl + m * 16 + ((lane >> 4) << 2) + r;
        int col  = (pf << 4) + (lane & 15);
        *(bfu*)(ldsY + rloc * 128 + (((col >> 3) ^ (rloc & 7)) << 4) + (col & 7) * 2) = f2bf(acc[m][pf][r]);
      }
  __syncthreads();
  int cg0 = (h << 7) + (ph << 6);
  #pragma unroll
  for (int j = 0; j < 8; ++j){
    int idx = j * 256 + t;              // 0..2047
    int row = idx >> 3, g = idx & 7;
    uint4 yv = *(const uint4*)(ldsY + row * 128 + ((g ^ (row & 7)) << 4));
    size_t rowg = rowbase + row;
    uint4 zv4 = *(const uint4*)(z16 + rowg * kDI + cg0 + g * 8);
    const bfu* yp = (const bfu*)&yv;
    const bfu* zp = (const bfu*)&zv4;
    uint4 out; bfu* op = (bfu*)&out;
    #pragma unroll
    for (int e = 0; e < 8; ++e){
      float zv = bf2f(zp[e]);
      float sg = zv / (1.f + __expf(-zv));
      op[e] = f2bf(bf2f(yp[e]) * sg);
    }
    *(uint4*)(y16 + rowg * kLDY + cg0 + g * 8) = out;
  }
}

// ---------------- RMS factors: rs[row] = rsqrt(mean(y^2)+eps) ----------------
__global__ __launch_bounds__(256) void k_rms(const bfu* __restrict__ y, float* __restrict__ rs){
  int row = blockIdx.x;
  int t = threadIdx.x, lane = t & 63, wave = t >> 6;
  const bfu* yp = y + (size_t)row * kLDY;
  uint4 a = *(const uint4*)(yp + t * 8);
  uint4 b = *(const uint4*)(yp + 2048 + t * 8);
  const bfu* ap = (const bfu*)&a;
  const bfu* bp = (const bfu*)&b;
  float ss = 0.f;
  #pragma unroll
  for (int j = 0; j < 8; ++j){
    float va = bf2f(ap[j]); ss += va * va;
    float vb = bf2f(bp[j]); ss += vb * vb;
  }
  #pragma unroll
  for (int o = 32; o > 0; o >>= 1) ss += __shfl_down(ss, o, 64);
  __shared__ float red[4];
  if (lane == 0) red[wave] = ss;
  __syncthreads();
  if (t == 0){
    float tot = red[0] + red[1] + red[2] + red[3];
    rs[row] = rsqrtf(tot * (1.f / 4096.f) + 1e-5f);
  }
}

extern "C" void kernel_launch(void* const* d_in, const int* in_sizes, int n_in,
                              void* d_out, int out_size, void* d_ws, size_t ws_size,
                              hipStream_t stream){
  (void)in_sizes; (void)n_in; (void)out_size; (void)ws_size;
  const float* u       = (const float*)d_in[0];
  const float* W_in    = (const float*)d_in[1];
  const float* conv_w  = (const float*)d_in[2];
  const float* conv_b  = (const float*)d_in[3];
  const float* dt_bias = (const float*)d_in[4];
  const float* A_log   = (const float*)d_in[5];
  const float* Dp      = (const float*)d_in[6];
  const float* norm_w  = (const float*)d_in[7];
  const float* W_out   = (const float*)d_in[8];
  char* ws = (char*)d_ws;

  // Workspace layout: ~242.8 MB total, with lifetime overlays.
  const size_t o_z    = 0;                                     // z16 [8192][4096] bf16   67.11 MB
  const size_t o_xbc  = o_z   + (size_t)kBL * kDI * 2;         // xbc [8192][4256] bf16   69.73 MB -> y16 [8192][4160] after conv (68.2 MB)
  const size_t o_u16  = o_xbc + (size_t)kBL * kXBC * 2;        // u16 [8192][2048] bf16   33.55 MB -> states + woutT
  const size_t o_xT   = o_u16 + (size_t)kBL * kDM * 2;         // xT slot 67.11 MB (winT [8448][2112] = 35.7 MB lives here until GEMM1 ends)
  const size_t o_B16  = o_xT  + (size_t)kBL * kDI * 2;
  const size_t o_BT   = o_B16 + (size_t)kBL * kDS * 2;
  const size_t o_C16  = o_BT  + (size_t)kBL * kDS * 2;
  const size_t o_dtf  = o_C16 + (size_t)kBL * kDS * 2;
  const size_t o_acum = o_dtf + (size_t)kBL * kNH * 4;
  const size_t o_rs   = o_acum + (size_t)1024 * 256 * 4;       // rs [8192] f32, 32 KB
  // overlays:
  const size_t o_states = o_u16;                               // after GEMM1
  const size_t o_woutT  = o_u16 + (size_t)1024 * 8192 * 2;     // after GEMM1
  const size_t o_winT   = o_xT;                                // before conv
  const size_t o_y16    = o_xbc;                               // after conv+dtscan

  bfu* z16    = (bfu*)(ws + o_z);
  bfu* xbc    = (bfu*)(ws + o_xbc);
  bfu* u16    = (bfu*)(ws + o_u16);
  bfu* xT     = (bfu*)(ws + o_xT);
  bfu* B16    = (bfu*)(ws + o_B16);
  bfu* BT     = (bfu*)(ws + o_BT);
  bfu* C16    = (bfu*)(ws + o_C16);
  float* dtf  = (float*)(ws + o_dtf);
  float* acum = (float*)(ws + o_acum);
  float* rs   = (float*)(ws + o_rs);
  bfu* statesS= (bfu*)(ws + o_states);
  bfu* woutT  = (bfu*)(ws + o_woutT);
  bfu* winT   = (bfu*)(ws + o_winT);
  bfu* y16    = (bfu*)(ws + o_y16);

  // allow 48 KiB dynamic LDS on the big GEMMs (idempotent, capture-safe)
  (void)hipFuncSetAttribute(reinterpret_cast<const void*>(&k_gemm256<2>),
                            hipFuncAttributeMaxDynamicSharedMemorySize, 49152);
  (void)hipFuncSetAttribute(reinterpret_cast<const void*>(&k_gemm256<0>),
                            hipFuncAttributeMaxDynamicSharedMemorySize, 49152);

  // zero the 96 pad rows of winT (rows kDP..kDPpad, width kLDW)
  k_zero<<<(96 * kLDW + 255) / 256, 256, 0, stream>>>(winT + (size_t)kDP * kLDW, 96 * kLDW);
  k_cvt<<<2048, 256, 0, stream>>>(u, u16, kBL * kDM / 8);
  k_transpose<<<dim3(kDP / 32, kDM / 32), dim3(32, 8), 0, stream>>>(W_in, winT, kDM, kDP, nullptr, kLDW);
  k_gemm256<2><<<(kDPpad / 128) * (kBL / 256), 512, 49152, stream>>>(u16, winT, nullptr, z16, xbc, nullptr, kDPpad / 128, kDPpad, kDM, kDM, kLDW);
  k_conv<<<dim3(kCV / 64, kBL / 64), 256, 0, stream>>>(xbc, conv_w, conv_b, xT, B16, BT, C16);
  k_dtscan<<<1024, 256, 0, stream>>>(xbc, dt_bias, A_log, dtf, acum);
  // woutT[n][k] = W_out[k][n] * norm_w[k]  (norm weight folded into weights)
  k_transpose<<<dim3(kDM / 32, kDI / 32), dim3(32, 8), 0, stream>>>(W_out, woutT, kDI, kDM, norm_w, kDI);
  k_states<<<1024, 256, 0, stream>>>(xT, BT, dtf, acum, statesS);
  k_scan<<<256, 256, 0, stream>>>(statesS, acum);
  k_y<<<dim3(1024, 2), 256, 0, stream>>>(xT, B16, C16, statesS, dtf, acum, z16, Dp, y16);
  k_rms<<<kBL, 256, 0, stream>>>(y16, rs);
  k_gemm256<0><<<(kDM / 128) * (kBL / 256), 512, 49152, stream>>>(y16, woutT, (float*)d_out, nullptr, nullptr, rs, kDM / 128, kDM, kDI, kLDY, kDI);
}

// Round 14
// 835.872 us; speedup vs baseline: 1.0191x; 1.0191x over previous
//
#include <hip/hip_runtime.h>

typedef short s8v __attribute__((ext_vector_type(8)));
typedef float f4v __attribute__((ext_vector_type(4)));
typedef unsigned short bfu;

#define MFMA16 __builtin_amdgcn_mfma_f32_16x16x32_bf16

constexpr int kSEQ = 4096;
constexpr int kBL  = 8192;   // BATCH*SEQLEN
constexpr int kDM  = 2048;   // D_MODEL
constexpr int kDP  = 8352;   // D_IN_PROJ
constexpr int kDPpad = 8448; // padded to 66*128
constexpr int kDI  = 4096;   // D_INNER
constexpr int kCV  = 4224;   // CONV_DIM
constexpr int kXBC = 4256;   // CONV_DIM + NHEADS (xBC | dt columns)
constexpr int kNH  = 32;
constexpr int kHD  = 128;
constexpr int kDS  = 64;
constexpr int kCH  = 256;    // CHUNK
constexpr int kLDW = 2112;   // winT row stride (breaks 4 KB power-of-2 alias)
constexpr int kLDY = 4160;   // y16 row stride (breaks 8 KB power-of-2 alias)

#if defined(__has_builtin)
#  if __has_builtin(__builtin_amdgcn_global_load_lds)
#    define HAS_GLD 1
#  endif
#endif
#ifndef HAS_GLD
#  define HAS_GLD 0
#endif

// Async 16B global->LDS. LDS dest is wave-uniform base + lane*16 (linear).
__device__ __forceinline__ void gld_lds16(const void* g, void* lbase, int lane){
#if HAS_GLD
  (void)lane;
  __builtin_amdgcn_global_load_lds(
      (const __attribute__((address_space(1))) void*)g,
      (__attribute__((address_space(3))) void*)lbase, 16, 0, 0);
#else
  *(uint4*)((char*)lbase + lane * 16) = *(const uint4*)g;
#endif
}

__device__ __forceinline__ bfu f2bf(float f){
  union { float f; unsigned u; } c; c.f = f;
  return (bfu)((c.u + 0x7fffu + ((c.u >> 16) & 1u)) >> 16);
}
__device__ __forceinline__ float bf2f(bfu s){
  union { unsigned u; float f; } c; c.u = ((unsigned)s) << 16;
  return c.f;
}

// Tiles are [R rows][64 bf16] = [R][8 slots of 16B], slot XOR-swizzled by (row&7).
__device__ __forceinline__ s8v frag_ld(const char* lds, int rowbase, int kh, int lane){
  int r = rowbase + (lane & 15);
  int slot = (kh << 2) + (lane >> 4);
  return *(const s8v*)(lds + (((r << 3) + (slot ^ (r & 7))) << 4));
}

// ---------------- zero fill (bf16 elements) ----------------
__global__ __launch_bounds__(256) void k_zero(bfu* __restrict__ p, int n){
  int i = blockIdx.x * 256 + threadIdx.x;
  if (i < n) p[i] = 0;
}

// ---------------- fp32 -> bf16 convert ----------------
__global__ __launch_bounds__(256) void k_cvt(const float* __restrict__ s, bfu* __restrict__ d, int n8){
  int i = blockIdx.x * 256 + threadIdx.x;
  int stride = gridDim.x * 256;
  for (; i < n8; i += stride){
    const float4* sp = (const float4*)(s + (size_t)i * 8);
    float4 a = sp[0], b = sp[1];
    uint4 pk; bfu* pp = (bfu*)&pk;
    pp[0]=f2bf(a.x); pp[1]=f2bf(a.y); pp[2]=f2bf(a.z); pp[3]=f2bf(a.w);
    pp[4]=f2bf(b.x); pp[5]=f2bf(b.y); pp[6]=f2bf(b.z); pp[7]=f2bf(b.w);
    *(uint4*)(d + (size_t)i * 8) = pk;
  }
}

// ---------------- fp32 [R][C] -> bf16 [C][R] transpose (dst ld = ldo), optional scale ----------------
__global__ __launch_bounds__(256) void k_transpose(const float* __restrict__ src, bfu* __restrict__ dst,
                                                   int R, int C, const float* __restrict__ scale, int ldo){
  __shared__ float tile[32][33];
  int c0 = blockIdx.x * 32, r0 = blockIdx.y * 32;
  int tx = threadIdx.x, ty = threadIdx.y;
  #pragma unroll
  for (int i = ty; i < 32; i += 8){
    int r = r0 + i, cc = c0 + tx;
    tile[i][tx] = (r < R && cc < C) ? src[(size_t)r * C + cc] : 0.f;
  }
  __syncthreads();
  #pragma unroll
  for (int i = ty; i < 32; i += 8){
    int dr = c0 + i, dc = r0 + tx;
    if (dr < C && dc < R){
      float v = tile[tx][i];
      if (scale) v *= scale[dc];
      dst[(size_t)dr * ldo + dc] = f2bf(v);
    }
  }
}

// ============ 256x128 GEMM, 2-blocks/CU, 3-buffer ring, counted vmcnt ============
// out[M][N] = A[M][K] * Bt[N][K]^T, bf16 in, fp32 acc. A rows stride lda, Bt rows ldb.
// MODE 0: fp32 output (ldc = N), scaled per-row by rsv[]. MODE 2: bf16 split z/xbc.
// 8 waves (4 row x 2 col), wave tile 64x64, BK=32; 3 LDS bufs x 24 KB = 72 KB
// -> 2 blocks/CU (cross-block overlap, m114) with 2-tile-deep prefetch:
// tile tt stages tile tt+2 (3 gld/thread); end-of-tile vmcnt(3) drains tile
// tt+1's loads (in flight ~2 tile periods > HBM latency -> near-free) and
// leaves tt+2's 3 in flight. Buffer (tt+2)%3 was last read at tile tt-1,
// sealed by that tile's barrier. Tail: vmcnt(0) at tt >= nt-2.
// Band supertiles + granule involution retained (r12/r9-verified).
template<int MODE>
__global__ __launch_bounds__(512, 4) void k_gemm256(const bfu* __restrict__ A, const bfu* __restrict__ Bt,
                                                    float* __restrict__ outF, bfu* __restrict__ outZ,
                                                    bfu* __restrict__ outX, const float* __restrict__ rsv,
                                                    int tilesN, int N, int K, int lda, int ldb){
  extern __shared__ char lds[];         // 73728 B: 3 bufs x (A 16KB + B 8KB)
  int t = threadIdx.x, lane = t & 63, wave = t >> 6;
  int wr = wave >> 1, wc = wave & 1;    // 4 row-groups x 2 col-groups
  // bijective XCD swizzle (gridDim.x % 8 == 0 by construction)
  int nwg = gridDim.x;
  int bid = blockIdx.x;
  int cpx = nwg >> 3;
  int wg = (bid & 7) * cpx + (bid >> 3);
  // band-supertile mapping: tilesM % 4 == 0 for both call sites
  int bandSz = tilesN << 2;
  int band = wg / bandSz;
  int rem  = wg - band * bandSz;
  int tnTile = rem >> 2;
  int tmTile = (band << 2) + (rem & 3);
  int tm = tmTile << 8, tn = tnTile << 7;
  const bfu* Ab = A + (size_t)tm * lda;
  const bfu* Bb = Bt + (size_t)tn * ldb;

  // stage one 128-row x 32-col half (1 gld/thread): granule t -> row t>>2,
  // source chunk (t&3) ^ ((t>>3)&3)  [involution]
  int sr = t >> 2, scc = (t & 3) ^ ((t >> 3) & 3);
  auto stage_half = [&](const bfu* src, int ld, int ldsOfs, int kcol0){
    gld_lds16(src + (size_t)sr * ld + kcol0 + scc * 8,
              lds + ldsOfs + (wave << 10), lane);
  };
  auto stage_tile = [&](int bufOfs, int kc){
    stage_half(Ab, lda, bufOfs, kc);
    stage_half(Ab + (size_t)128 * lda, lda, bufOfs + 8192, kc);
    stage_half(Bb, ldb, bufOfs + 16384, kc);
  };
  // frag read swizzle: row-part collapses (frag row bases are multiples of 16)
  int swz = ((lane >> 4) ^ ((lane >> 1) & 3)) << 4;

  f4v acc[4][4];
  f4v zz = {0.f, 0.f, 0.f, 0.f};
  #pragma unroll
  for (int m = 0; m < 4; ++m)
    #pragma unroll
    for (int n = 0; n < 4; ++n) acc[m][n] = zz;

  int nt = K >> 5;                      // >= 64 always
  // prologue: stage tiles 0,1 into bufs 0,1; prove tile 0; barrier
  stage_tile(0, 0);
  stage_tile(24576, 32);
  __builtin_amdgcn_sched_barrier(0);
  asm volatile("s_waitcnt vmcnt(3)" ::: "memory");
  __builtin_amdgcn_sched_barrier(0);
  __builtin_amdgcn_s_barrier();
  __builtin_amdgcn_sched_barrier(0);

  int cbOfs = 0, n1Ofs = 24576, n2Ofs = 49152;
  #pragma unroll 1
  for (int tt = 0; tt < nt; ++tt){
    bool deep = (tt + 2 < nt);
    if (deep) stage_tile(n2Ofs, (tt + 2) << 5);
    s8v af[4], bf[4];
    #pragma unroll
    for (int m = 0; m < 4; ++m)
      af[m] = *(const s8v*)(lds + cbOfs + ((wr * 64 + m * 16 + (lane & 15)) << 6) + swz);
    #pragma unroll
    for (int n = 0; n < 4; ++n)
      bf[n] = *(const s8v*)(lds + cbOfs + 16384 + ((wc * 64 + n * 16 + (lane & 15)) << 6) + swz);
    __builtin_amdgcn_s_setprio(1);
    #pragma unroll
    for (int n = 0; n < 4; ++n)
      #pragma unroll
      for (int m = 0; m < 4; ++m)
        acc[m][n] = MFMA16(af[m], bf[n], acc[m][n], 0, 0, 0);
    __builtin_amdgcn_s_setprio(0);
    __builtin_amdgcn_sched_barrier(0);
    if (deep) { asm volatile("s_waitcnt vmcnt(3)" ::: "memory"); }
    else      { asm volatile("s_waitcnt vmcnt(0)" ::: "memory"); }
    __builtin_amdgcn_sched_barrier(0);
    __builtin_amdgcn_s_barrier();
    __builtin_amdgcn_sched_barrier(0);
    int tmp = cbOfs; cbOfs = n1Ofs; n1Ofs = n2Ofs; n2Ofs = tmp;
  }

  int r0 = (lane >> 4) << 2;
  if (MODE == 0){
    // stage per-row rs factors in LDS (staging region dead after final drain)
    float* rsl = (float*)lds;
    if (t < 256) rsl[t] = rsv[tm + t];
    __syncthreads();
    #pragma unroll
    for (int m = 0; m < 4; ++m)
      #pragma unroll
      for (int n = 0; n < 4; ++n)
        #pragma unroll
        for (int r = 0; r < 4; ++r){
          int rl = wr * 64 + m * 16 + r0 + r;
          size_t rg = (size_t)(tm + rl);
          int cg = tn + wc * 64 + n * 16 + (lane & 15);
          outF[rg * N + cg] = acc[m][n][r] * rsl[rl];
        }
  } else {
    // bf16 epilogue: restage C (256x128) in two 128-row halves of 32 KB
    bfu* op; int ldo, cofs;
    if (tn < 4096){ op = outZ; ldo = 4096; cofs = 0; }
    else          { op = outX; ldo = kXBC; cofs = 4096; }
    #pragma unroll
    for (int h = 0; h < 2; ++h){
      __syncthreads();
      if ((wr >> 1) == h){
        #pragma unroll
        for (int m = 0; m < 4; ++m)
          #pragma unroll
          for (int n = 0; n < 4; ++n){
            int col = wc * 64 + n * 16 + (lane & 15);
            int cs = col >> 3, cl = col & 7;
            #pragma unroll
            for (int r = 0; r < 4; ++r){
              int row = (wr & 1) * 64 + m * 16 + r0 + r;   // local 0..127
              *(bfu*)(lds + row * 256 + ((cs ^ (row & 7)) << 4) + cl * 2) = f2bf(acc[m][n][r]);
            }
          }
      }
      __syncthreads();
      int row = t >> 2;                  // 0..127
      bfu* baseo = op + (size_t)(tm + h * 128 + row) * ldo + (tn - cofs);
      #pragma unroll
      for (int i = 0; i < 4; ++i){
        int g = (t & 3) * 4 + i;         // 16 granules of 16B per 256B row
        int cg = tn + g * 8;
        if (cg < kDP){
          uint4 v = *(const uint4*)(lds + row * 256 + ((g ^ (row & 7)) << 4));
          *(uint4*)(baseo + g * 8) = v;
        }
      }
    }
  }
}

// ---------------- causal depthwise conv4 + bias + SiLU; emits xT, B, BT, C ----------------
__global__ __launch_bounds__(256) void k_conv(const bfu* __restrict__ xbc, const float* __restrict__ cw,
    const float* __restrict__ cb, bfu* __restrict__ xT,
    bfu* __restrict__ B16o, bfu* __restrict__ BTo, bfu* __restrict__ C16o){
  int cht = blockIdx.x;                 // 0..65 channel tile (over CONV_DIM)
  int lt = blockIdx.y;                  // 0..127 seq tile over b*l
  int b = lt >> 6;
  int l0 = (lt & 63) << 6;
  int t = threadIdx.x;
  __shared__ float w[256];
  __shared__ float bias[64];
  __shared__ bfu in16[67][66];
  __shared__ bfu out16[64][66];
  if (t < 64) bias[t] = cb[cht * 64 + t];
  w[t] = cw[cht * 256 + t];
  int chbase = cht * 64;
  for (int i = t; i < 67 * 64; i += 256){
    int rrow = i >> 6, cc = i & 63;
    int l = l0 + rrow - 3;
    bfu hv = 0;
    if (l >= 0) hv = xbc[((size_t)b * kSEQ + l) * kXBC + chbase + cc];
    in16[rrow][cc] = hv;
  }
  __syncthreads();
  for (int i = t; i < 4096; i += 256){
    int lr = i >> 6, cc = i & 63;
    float acc = bias[cc];
    #pragma unroll
    for (int j = 0; j < 4; ++j)
      acc += bf2f(in16[lr + j][cc]) * w[cc * 4 + j];
    float sv = acc / (1.f + __expf(-acc));
    out16[lr][cc] = f2bf(sv);
  }
  __syncthreads();
  // row-major outputs: B and C only
  if (chbase >= 4096){
    for (int i = t; i < 4096; i += 256){
      int lr = i >> 6, cc = i & 63;
      size_t row = (size_t)b * kSEQ + l0 + lr;
      int ch = chbase + cc;
      bfu v = out16[lr][cc];
      if (ch < 4096 + kDS) B16o[row * kDS + (ch - 4096)] = v;
      else                 C16o[row * kDS + (ch - 4096 - kDS)] = v;
    }
  }
  // transposed outputs: x -> xT, B -> BT
  if (chbase < 4096 + kDS){
    for (int i = t; i < 4096; i += 256){
      int cc = i >> 6, lr = i & 63;
      int ch = chbase + cc;
      int lg = l0 + lr;
      bfu v = out16[lr][cc];
      if (ch < 4096){
        int hh = ch >> 7, p = ch & 127;
        xT[(((size_t)b * kNH + hh) * kHD + p) * kSEQ + lg] = v;
      } else if (ch < 4096 + kDS){
        BTo[((size_t)b * kDS + (ch - 4096)) * kSEQ + lg] = v;
      }
    }
  }
}

// ---------------- dt = softplus(raw + bias); dA = -exp(A_log)*dt; per-chunk inclusive cumsum ----------------
__global__ __launch_bounds__(256) void k_dtscan(const bfu* __restrict__ xbc, const float* __restrict__ dt_bias,
    const float* __restrict__ A_log, float* __restrict__ dtf, float* __restrict__ acum){
  int bi = blockIdx.x;                  // ((b*16+c)*32+h)
  int h = bi & 31, c = (bi >> 5) & 15, b = bi >> 9;
  int t = threadIdx.x;
  size_t row = (size_t)b * kSEQ + c * kCH + t;
  float draw = bf2f(xbc[row * kXBC + kCV + h]) + dt_bias[h];
  float dt = (draw > 20.f) ? draw : log1pf(__expf(draw));
  dtf[row * kNH + h] = dt;
  float dA = -__expf(A_log[h]) * dt;
  __shared__ float s[256];
  s[t] = dA;
  __syncthreads();
  #pragma unroll
  for (int off = 1; off < 256; off <<= 1){
    float v = (t >= off) ? s[t - off] : 0.f;
    __syncthreads();
    s[t] += v;
    __syncthreads();
  }
  acum[(size_t)bi * 256 + t] = s[t];
}

// ---------------- per-chunk local states[p][n] = sum_l Xt[p][l] * B[l][n]*dt[l]*exp(Atot-Acum[l]) ----------------
__global__ __launch_bounds__(256) void k_states(const bfu* __restrict__ xT, const bfu* __restrict__ BT,
    const float* __restrict__ dtf, const float* __restrict__ acum, bfu* __restrict__ states){
  int bi = blockIdx.x;
  int h = bi & 31, c = (bi >> 5) & 15, b = bi >> 9;
  int t = threadIdx.x, lane = t & 63, wave = t >> 6;
  int wr = wave >> 1, wc = wave & 1;
  __shared__ uint4 ldsX4[1024];         // [128 p][64 l] bf16
  __shared__ uint4 ldsB4[512];          // [64 n][64 l] bf16 (scaled)
  __shared__ float dsv[256];
  char* ldsX = (char*)ldsX4;
  char* ldsB = (char*)ldsB4;
  float Atot = acum[(size_t)bi * 256 + 255];
  {
    size_t row = (size_t)b * kSEQ + c * kCH + t;
    dsv[t] = dtf[row * kNH + h] * __expf(Atot - acum[(size_t)bi * 256 + t]);
  }
  f4v zz = {0.f, 0.f, 0.f, 0.f};
  f4v acc[4][2];
  #pragma unroll
  for (int m = 0; m < 4; ++m){ acc[m][0] = zz; acc[m][1] = zz; }
  const bfu* xTp = xT + ((size_t)b * kNH + h) * kHD * kSEQ + c * kCH;
  const bfu* BTp = BT + (size_t)b * kDS * kSEQ + c * kCH;
  __syncthreads();
  for (int kb = 0; kb < 4; ++kb){
    #pragma unroll
    for (int it = 0; it < 4; ++it){
      int s = it * 256 + t;
      int row = s >> 3;
      int srcslot = (s & 7) ^ (row & 7);
      gld_lds16(xTp + (size_t)row * kSEQ + kb * 64 + srcslot * 8,
                ldsX + it * 4096 + wave * 1024, lane);
    }
    #pragma unroll
    for (int it = 0; it < 2; ++it){
      int cidx = it * 256 + t;
      int row = cidx >> 3, slot = cidx & 7;
      uint4 v = *(const uint4*)(BTp + (size_t)row * kSEQ + kb * 64 + slot * 8);
      bfu* hp = (bfu*)&v;
      #pragma unroll
      for (int j = 0; j < 8; ++j)
        hp[j] = f2bf(bf2f(hp[j]) * dsv[kb * 64 + slot * 8 + j]);
      *(uint4*)(ldsB + (((row << 3) + (slot ^ (row & 7))) << 4)) = v;
    }
    __syncthreads();
    s8v af[4][2], bb[2][2];
    #pragma unroll
    for (int m = 0; m < 4; ++m){
      af[m][0] = frag_ld(ldsX, wr * 64 + m * 16, 0, lane);
      af[m][1] = frag_ld(ldsX, wr * 64 + m * 16, 1, lane);
    }
    #pragma unroll
    for (int nf = 0; nf < 2; ++nf){
      bb[nf][0] = frag_ld(ldsB, wc * 32 + nf * 16, 0, lane);
      bb[nf][1] = frag_ld(ldsB, wc * 32 + nf * 16, 1, lane);
    }
    #pragma unroll
    for (int kh = 0; kh < 2; ++kh)
      #pragma unroll
      for (int m = 0; m < 4; ++m)
        #pragma unroll
        for (int nf = 0; nf < 2; ++nf)
          acc[m][nf] = MFMA16(af[m][kh], bb[nf][kh], acc[m][nf], 0, 0, 0);
    __syncthreads();
  }
  bfu* sp = states + (size_t)bi * 8192;
  int r0 = (lane >> 4) << 2;
  #pragma unroll
  for (int m = 0; m < 4; ++m)
    #pragma unroll
    for (int nf = 0; nf < 2; ++nf)
      #pragma unroll
      for (int r = 0; r < 4; ++r){
        int p = wr * 64 + m * 16 + r0 + r;
        int n = wc * 32 + nf * 16 + (lane & 15);
        sp[p * 64 + n] = f2bf(acc[m][nf][r]);
      }
}

// ---------------- inter-chunk state recurrence (in-place; split over 4 j-groups) ----------------
__global__ __launch_bounds__(256) void k_scan(bfu* __restrict__ st, const float* __restrict__ acum){
  int bh = blockIdx.x >> 2;             // 0..63  (b*32+h)
  int jg = blockIdx.x & 3;              // 0..3
  int b = bh >> 5, h = bh & 31;
  int t = threadIdx.x;
  float run[8];
  #pragma unroll
  for (int j = 0; j < 8; ++j) run[j] = 0.f;
  for (int c = 0; c < 16; ++c){
    size_t bi = (size_t)((b * 16 + c) * 32 + h);
    float eT = __expf(acum[bi * 256 + 255]);
    size_t base = bi * 8192 + (size_t)jg * 2048;
    #pragma unroll
    for (int j = 0; j < 8; ++j){
      size_t idx = base + j * 256 + t;
      float sl = bf2f(st[idx]);
      st[idx] = f2bf(run[j]);
      run[j] = run[j] * eT + sl;
    }
  }
}

// ---------------- Y = (P + D*I)X + Y_off, * silu(z) -> y16 (bf16, [BL][kLDY]) ----------------
__global__ __launch_bounds__(256) void k_y(
    const bfu* __restrict__ xT, const bfu* __restrict__ Bm, const bfu* __restrict__ Cm,
    const bfu* __restrict__ SIs, const float* __restrict__ dtf, const float* __restrict__ acum,
    const bfu* __restrict__ z16, const float* __restrict__ Dp,
    bfu* __restrict__ y16)
{
  int bi = blockIdx.x;
  int h = bi & 31, c = (bi >> 5) & 15, b = bi >> 9;
  int ph = blockIdx.y;                  // p half (64 cols)
  int t = threadIdx.x, lane = t & 63, wave = t >> 6;
  int wl = wave << 6;                   // wave's 64 rows of the chunk
  __shared__ uint4 ldsP4[2048];         // per-wave P [64][64] bf16, 4x8KB; reused as Y restage
  __shared__ uint4 ldsT4[512];          // SI tile then Xt tiles [64][64] bf16
  __shared__ float acumS[256];
  __shared__ float dtS[256];
  char* ldsP = ((char*)ldsP4) + (wave << 13);
  char* ldsT = (char*)ldsT4;
  size_t rowbase = (size_t)b * kSEQ + c * kCH;
  acumS[t] = acum[(size_t)bi * 256 + t];
  dtS[t] = dtf[(rowbase + t) * kNH + h];
  const bfu* SIp = SIs + (size_t)bi * 8192 + (size_t)ph * 4096;  // [64 p][64 n] bf16
  #pragma unroll
  for (int it = 0; it < 2; ++it){
    int cidx = it * 256 + t;
    int row = cidx >> 3, slot = cidx & 7;
    uint4 v = *(const uint4*)(SIp + row * 64 + slot * 8);
    *(uint4*)(ldsT + (((row << 3) + (slot ^ (row & 7))) << 4)) = v;
  }
  const bfu* Cp = Cm + rowbase * kDS;
  s8v cf[4][2];
  #pragma unroll
  for (int m = 0; m < 4; ++m){
    cf[m][0] = *(const s8v*)(Cp + (size_t)(wl + m * 16 + (lane & 15)) * kDS + ((lane >> 4) << 3));
    cf[m][1] = *(const s8v*)(Cp + (size_t)(wl + m * 16 + (lane & 15)) * kDS + 32 + ((lane >> 4) << 3));
  }
  __syncthreads();
  float Arow[16];
  #pragma unroll
  for (int m = 0; m < 4; ++m)
    #pragma unroll
    for (int r = 0; r < 4; ++r)
      Arow[m * 4 + r] = acumS[wl + m * 16 + ((lane >> 4) << 2) + r];
  f4v acc[4][4];
  {
    s8v bfo[4][2];
    #pragma unroll
    for (int pf = 0; pf < 4; ++pf){
      bfo[pf][0] = frag_ld(ldsT, pf << 4, 0, lane);
      bfo[pf][1] = frag_ld(ldsT, pf << 4, 1, lane);
    }
    f4v zz = {0.f, 0.f, 0.f, 0.f};
    #pragma unroll
    for (int m = 0; m < 4; ++m)
      #pragma unroll
      for (int pf = 0; pf < 4; ++pf){
        f4v v = zz;
        v = MFMA16(cf[m][0], bfo[pf][0], v, 0, 0, 0);
        v = MFMA16(cf[m][1], bfo[pf][1], v, 0, 0, 0);
        #pragma unroll
        for (int r = 0; r < 4; ++r) v[r] *= __expf(Arow[m * 4 + r]);
        acc[m][pf] = v;
      }
  }
  float Dh = Dp[h];
  const bfu* Bp = Bm + rowbase * kDS;
  const bfu* xTp = xT + (((size_t)b * kNH + h) * kHD + ph * 64) * kSEQ + c * kCH;
  #pragma unroll 1
  for (int sb = 0; sb < 4; ++sb){
    __syncthreads();
    #pragma unroll
    for (int it = 0; it < 2; ++it){
      int s = it * 256 + t;
      int row = s >> 3;
      int srcslot = (s & 7) ^ (row & 7);
      gld_lds16(xTp + (size_t)row * kSEQ + sb * 64 + srcslot * 8,
                ldsT + it * 4096 + wave * 1024, lane);
    }
    f4v sv[4][4];
    {
      s8v bsf[4][2];
      #pragma unroll
      for (int sf = 0; sf < 4; ++sf){
        bsf[sf][0] = *(const s8v*)(Bp + (size_t)(sb * 64 + sf * 16 + (lane & 15)) * kDS + ((lane >> 4) << 3));
        bsf[sf][1] = *(const s8v*)(Bp + (size_t)(sb * 64 + sf * 16 + (lane & 15)) * kDS + 32 + ((lane >> 4) << 3));
      }
      f4v zz = {0.f, 0.f, 0.f, 0.f};
      #pragma unroll
      for (int m = 0; m < 4; ++m)
        #pragma unroll
        for (int sf = 0; sf < 4; ++sf){
          f4v v = zz;
          v = MFMA16(cf[m][0], bsf[sf][0], v, 0, 0, 0);
          v = MFMA16(cf[m][1], bsf[sf][1], v, 0, 0, 0);
          sv[m][sf] = v;
        }
    }
    int scb = sb << 6;
    float As[4], dts_[4];
    #pragma unroll
    for (int sf = 0; sf < 4; ++sf){
      As[sf] = acumS[scb + sf * 16 + (lane & 15)];
      dts_[sf] = dtS[scb + sf * 16 + (lane & 15)];
    }
    #pragma unroll
    for (int m = 0; m < 4; ++m)
      #pragma unroll
      for (int sf = 0; sf < 4; ++sf)
        #pragma unroll
        for (int r = 0; r < 4; ++r){
          int rloc = m * 16 + ((lane >> 4) << 2) + r;
          int scl = sf * 16 + (lane & 15);
          int d = (wl + rloc) - (scb + scl);
          float pv = 0.f;
          if (d >= 0)
            pv = sv[m][sf][r] * __expf(Arow[m * 4 + r] - As[sf]) * dts_[sf];
          if (d == 0)
            pv += Dh;                   // D-skip folded into P diagonal
          *(bfu*)(ldsP + rloc * 128 + ((((scl >> 3) ^ (rloc & 7)) << 3) + (scl & 7)) * 2) = f2bf(pv);
        }
    __syncthreads();
    s8v xb[4][2];
    #pragma unroll
    for (int pf = 0; pf < 4; ++pf){
      xb[pf][0] = frag_ld(ldsT, pf << 4, 0, lane);
      xb[pf][1] = frag_ld(ldsT, pf << 4, 1, lane);
    }
    #pragma unroll
    for (int m = 0; m < 4; ++m){
      s8v pa0 = frag_ld(ldsP, m << 4, 0, lane);
      s8v pa1 = frag_ld(ldsP, m << 4, 1, lane);
      #pragma unroll
      for (int pf = 0; pf < 4; ++pf){
        acc[m][pf] = MFMA16(pa0, xb[pf][0], acc[m][pf], 0, 0, 0);
        acc[m][pf] = MFMA16(pa1, xb[pf][1], acc[m][pf], 0, 0, 0);
      }
    }
  }
  // ---- coalesced gated epilogue: restage Y tile [256 rows][64 cols] through LDS ----
  __syncthreads();
  char* ldsY = (char*)ldsP4;            // full 32KB, slot^row&7 swizzled rows of 128B
  #pragma unroll
  for (int m = 0; m < 4; ++m)
    #pragma unroll
    for (int pf = 0; pf < 4; ++pf)
      #pragma unroll
      for (int r = 0; r < 4; ++r){
        int rloc = wl + m * 16 + ((lane >> 4) << 2) + r;
        int col  = (pf << 4) + (lane & 15);
        *(bfu*)(ldsY + rloc * 128 + (((col >> 3) ^ (rloc & 7)) << 4) + (col & 7) * 2) = f2bf(acc[m][pf][r]);
      }
  __syncthreads();
  int cg0 = (h << 7) + (ph << 6);
  #pragma unroll
  for (int j = 0; j < 8; ++j){
    int idx = j * 256 + t;              // 0..2047
    int row = idx >> 3, g = idx & 7;
    uint4 yv = *(const uint4*)(ldsY + row * 128 + ((g ^ (row & 7)) << 4));
    size_t rowg = rowbase + row;
    uint4 zv4 = *(const uint4*)(z16 + rowg * kDI + cg0 + g * 8);
    const bfu* yp = (const bfu*)&yv;
    const bfu* zp = (const bfu*)&zv4;
    uint4 out; bfu* op = (bfu*)&out;
    #pragma unroll
    for (int e = 0; e < 8; ++e){
      float zv = bf2f(zp[e]);
      float sg = zv / (1.f + __expf(-zv));
      op[e] = f2bf(bf2f(yp[e]) * sg);
    }
    *(uint4*)(y16 + rowg * kLDY + cg0 + g * 8) = out;
  }
}

// ---------------- RMS factors: rs[row] = rsqrt(mean(y^2)+eps) ----------------
__global__ __launch_bounds__(256) void k_rms(const bfu* __restrict__ y, float* __restrict__ rs){
  int row = blockIdx.x;
  int t = threadIdx.x, lane = t & 63, wave = t >> 6;
  const bfu* yp = y + (size_t)row * kLDY;
  uint4 a = *(const uint4*)(yp + t * 8);
  uint4 b = *(const uint4*)(yp + 2048 + t * 8);
  const bfu* ap = (const bfu*)&a;
  const bfu* bp = (const bfu*)&b;
  float ss = 0.f;
  #pragma unroll
  for (int j = 0; j < 8; ++j){
    float va = bf2f(ap[j]); ss += va * va;
    float vb = bf2f(bp[j]); ss += vb * vb;
  }
  #pragma unroll
  for (int o = 32; o > 0; o >>= 1) ss += __shfl_down(ss, o, 64);
  __shared__ float red[4];
  if (lane == 0) red[wave] = ss;
  __syncthreads();
  if (t == 0){
    float tot = red[0] + red[1] + red[2] + red[3];
    rs[row] = rsqrtf(tot * (1.f / 4096.f) + 1e-5f);
  }
}

extern "C" void kernel_launch(void* const* d_in, const int* in_sizes, int n_in,
                              void* d_out, int out_size, void* d_ws, size_t ws_size,
                              hipStream_t stream){
  (void)in_sizes; (void)n_in; (void)out_size; (void)ws_size;
  const float* u       = (const float*)d_in[0];
  const float* W_in    = (const float*)d_in[1];
  const float* conv_w  = (const float*)d_in[2];
  const float* conv_b  = (const float*)d_in[3];
  const float* dt_bias = (const float*)d_in[4];
  const float* A_log   = (const float*)d_in[5];
  const float* Dp      = (const float*)d_in[6];
  const float* norm_w  = (const float*)d_in[7];
  const float* W_out   = (const float*)d_in[8];
  char* ws = (char*)d_ws;

  // Workspace layout: ~242.8 MB total, with lifetime overlays.
  const size_t o_z    = 0;                                     // z16 [8192][4096] bf16   67.11 MB
  const size_t o_xbc  = o_z   + (size_t)kBL * kDI * 2;         // xbc [8192][4256] bf16   69.73 MB -> y16 [8192][4160] after conv (68.2 MB)
  const size_t o_u16  = o_xbc + (size_t)kBL * kXBC * 2;        // u16 [8192][2048] bf16   33.55 MB -> states + woutT
  const size_t o_xT   = o_u16 + (size_t)kBL * kDM * 2;         // xT slot 67.11 MB (winT [8448][2112] = 35.7 MB lives here until GEMM1 ends)
  const size_t o_B16  = o_xT  + (size_t)kBL * kDI * 2;
  const size_t o_BT   = o_B16 + (size_t)kBL * kDS * 2;
  const size_t o_C16  = o_BT  + (size_t)kBL * kDS * 2;
  const size_t o_dtf  = o_C16 + (size_t)kBL * kDS * 2;
  const size_t o_acum = o_dtf + (size_t)kBL * kNH * 4;
  const size_t o_rs   = o_acum + (size_t)1024 * 256 * 4;       // rs [8192] f32, 32 KB
  // overlays:
  const size_t o_states = o_u16;                               // after GEMM1
  const size_t o_woutT  = o_u16 + (size_t)1024 * 8192 * 2;     // after GEMM1
  const size_t o_winT   = o_xT;                                // before conv
  const size_t o_y16    = o_xbc;                               // after conv+dtscan

  bfu* z16    = (bfu*)(ws + o_z);
  bfu* xbc    = (bfu*)(ws + o_xbc);
  bfu* u16    = (bfu*)(ws + o_u16);
  bfu* xT     = (bfu*)(ws + o_xT);
  bfu* B16    = (bfu*)(ws + o_B16);
  bfu* BT     = (bfu*)(ws + o_BT);
  bfu* C16    = (bfu*)(ws + o_C16);
  float* dtf  = (float*)(ws + o_dtf);
  float* acum = (float*)(ws + o_acum);
  float* rs   = (float*)(ws + o_rs);
  bfu* statesS= (bfu*)(ws + o_states);
  bfu* woutT  = (bfu*)(ws + o_woutT);
  bfu* winT   = (bfu*)(ws + o_winT);
  bfu* y16    = (bfu*)(ws + o_y16);

  // allow 72 KiB dynamic LDS on the big GEMMs (idempotent, capture-safe)
  (void)hipFuncSetAttribute(reinterpret_cast<const void*>(&k_gemm256<2>),
                            hipFuncAttributeMaxDynamicSharedMemorySize, 73728);
  (void)hipFuncSetAttribute(reinterpret_cast<const void*>(&k_gemm256<0>),
                            hipFuncAttributeMaxDynamicSharedMemorySize, 73728);

  // zero the 96 pad rows of winT (rows kDP..kDPpad, width kLDW)
  k_zero<<<(96 * kLDW + 255) / 256, 256, 0, stream>>>(winT + (size_t)kDP * kLDW, 96 * kLDW);
  k_cvt<<<2048, 256, 0, stream>>>(u, u16, kBL * kDM / 8);
  k_transpose<<<dim3(kDP / 32, kDM / 32), dim3(32, 8), 0, stream>>>(W_in, winT, kDM, kDP, nullptr, kLDW);
  k_gemm256<2><<<(kDPpad / 128) * (kBL / 256), 512, 73728, stream>>>(u16, winT, nullptr, z16, xbc, nullptr, kDPpad / 128, kDPpad, kDM, kDM, kLDW);
  k_conv<<<dim3(kCV / 64, kBL / 64), 256, 0, stream>>>(xbc, conv_w, conv_b, xT, B16, BT, C16);
  k_dtscan<<<1024, 256, 0, stream>>>(xbc, dt_bias, A_log, dtf, acum);
  // woutT[n][k] = W_out[k][n] * norm_w[k]  (norm weight folded into weights)
  k_transpose<<<dim3(kDM / 32, kDI / 32), dim3(32, 8), 0, stream>>>(W_out, woutT, kDI, kDM, norm_w, kDI);
  k_states<<<1024, 256, 0, stream>>>(xT, BT, dtf, acum, statesS);
  k_scan<<<256, 256, 0, stream>>>(statesS, acum);
  k_y<<<dim3(1024, 2), 256, 0, stream>>>(xT, B16, C16, statesS, dtf, acum, z16, Dp, y16);
  k_rms<<<kBL, 256, 0, stream>>>(y16, rs);
  k_gemm256<0><<<(kDM / 128) * (kBL / 256), 512, 73728, stream>>>(y16, woutT, (float*)d_out, nullptr, nullptr, rs, kDM / 128, kDM, kDI, kLDY, kDI);
}

// Round 15
// 740.267 us; speedup vs baseline: 1.1507x; 1.1291x over previous
//
#include <hip/hip_runtime.h>

typedef short s8v __attribute__((ext_vector_type(8)));
typedef float f4v __attribute__((ext_vector_type(4)));
typedef unsigned short bfu;

#define MFMA16 __builtin_amdgcn_mfma_f32_16x16x32_bf16

constexpr int kSEQ = 4096;
constexpr int kBL  = 8192;   // BATCH*SEQLEN
constexpr int kDM  = 2048;   // D_MODEL
constexpr int kDP  = 8352;   // D_IN_PROJ
constexpr int kDPpad = 8448; // padded to 66*128
constexpr int kDI  = 4096;   // D_INNER
constexpr int kCV  = 4224;   // CONV_DIM
constexpr int kXBC = 4256;   // CONV_DIM + NHEADS (xBC | dt columns)
constexpr int kNH  = 32;
constexpr int kHD  = 128;
constexpr int kDS  = 64;
constexpr int kCH  = 256;    // CHUNK
constexpr int kLDW = 2112;   // winT row stride (breaks 4 KB power-of-2 alias)
constexpr int kLDY = 4160;   // y16 row stride (breaks 8 KB power-of-2 alias)

#if defined(__has_builtin)
#  if __has_builtin(__builtin_amdgcn_global_load_lds)
#    define HAS_GLD 1
#  endif
#endif
#ifndef HAS_GLD
#  define HAS_GLD 0
#endif

// Async 16B global->LDS. LDS dest is wave-uniform base + lane*16 (linear).
__device__ __forceinline__ void gld_lds16(const void* g, void* lbase, int lane){
#if HAS_GLD
  (void)lane;
  __builtin_amdgcn_global_load_lds(
      (const __attribute__((address_space(1))) void*)g,
      (__attribute__((address_space(3))) void*)lbase, 16, 0, 0);
#else
  *(uint4*)((char*)lbase + lane * 16) = *(const uint4*)g;
#endif
}

__device__ __forceinline__ bfu f2bf(float f){
  union { float f; unsigned u; } c; c.f = f;
  return (bfu)((c.u + 0x7fffu + ((c.u >> 16) & 1u)) >> 16);
}
__device__ __forceinline__ float bf2f(bfu s){
  union { unsigned u; float f; } c; c.u = ((unsigned)s) << 16;
  return c.f;
}

// Tiles are [R rows][64 bf16] = [R][8 slots of 16B], slot XOR-swizzled by (row&7).
__device__ __forceinline__ s8v frag_ld(const char* lds, int rowbase, int kh, int lane){
  int r = rowbase + (lane & 15);
  int slot = (kh << 2) + (lane >> 4);
  return *(const s8v*)(lds + (((r << 3) + (slot ^ (r & 7))) << 4));
}

// ---------------- zero fill (bf16 elements) ----------------
__global__ __launch_bounds__(256) void k_zero(bfu* __restrict__ p, int n){
  int i = blockIdx.x * 256 + threadIdx.x;
  if (i < n) p[i] = 0;
}

// ---------------- fp32 -> bf16 convert ----------------
__global__ __launch_bounds__(256) void k_cvt(const float* __restrict__ s, bfu* __restrict__ d, int n8){
  int i = blockIdx.x * 256 + threadIdx.x;
  int stride = gridDim.x * 256;
  for (; i < n8; i += stride){
    const float4* sp = (const float4*)(s + (size_t)i * 8);
    float4 a = sp[0], b = sp[1];
    uint4 pk; bfu* pp = (bfu*)&pk;
    pp[0]=f2bf(a.x); pp[1]=f2bf(a.y); pp[2]=f2bf(a.z); pp[3]=f2bf(a.w);
    pp[4]=f2bf(b.x); pp[5]=f2bf(b.y); pp[6]=f2bf(b.z); pp[7]=f2bf(b.w);
    *(uint4*)(d + (size_t)i * 8) = pk;
  }
}

// ---------------- fp32 [R][C] -> bf16 [C][R] transpose (dst ld = ldo), optional scale ----------------
__global__ __launch_bounds__(256) void k_transpose(const float* __restrict__ src, bfu* __restrict__ dst,
                                                   int R, int C, const float* __restrict__ scale, int ldo){
  __shared__ float tile[32][33];
  int c0 = blockIdx.x * 32, r0 = blockIdx.y * 32;
  int tx = threadIdx.x, ty = threadIdx.y;
  #pragma unroll
  for (int i = ty; i < 32; i += 8){
    int r = r0 + i, cc = c0 + tx;
    tile[i][tx] = (r < R && cc < C) ? src[(size_t)r * C + cc] : 0.f;
  }
  __syncthreads();
  #pragma unroll
  for (int i = ty; i < 32; i += 8){
    int dr = c0 + i, dc = r0 + tx;
    if (dr < C && dc < R){
      float v = tile[tx][i];
      if (scale) v *= scale[dc];
      dst[(size_t)dr * ldo + dc] = f2bf(v);
    }
  }
}

// ============ 256x128 GEMM, 2-blocks/CU, 3-buffer ring, counted vmcnt (r14, frozen) ============
template<int MODE>
__global__ __launch_bounds__(512, 4) void k_gemm256(const bfu* __restrict__ A, const bfu* __restrict__ Bt,
                                                    float* __restrict__ outF, bfu* __restrict__ outZ,
                                                    bfu* __restrict__ outX, const float* __restrict__ rsv,
                                                    int tilesN, int N, int K, int lda, int ldb){
  extern __shared__ char lds[];         // 73728 B: 3 bufs x (A 16KB + B 8KB)
  int t = threadIdx.x, lane = t & 63, wave = t >> 6;
  int wr = wave >> 1, wc = wave & 1;    // 4 row-groups x 2 col-groups
  int nwg = gridDim.x;
  int bid = blockIdx.x;
  int cpx = nwg >> 3;
  int wg = (bid & 7) * cpx + (bid >> 3);
  int bandSz = tilesN << 2;
  int band = wg / bandSz;
  int rem  = wg - band * bandSz;
  int tnTile = rem >> 2;
  int tmTile = (band << 2) + (rem & 3);
  int tm = tmTile << 8, tn = tnTile << 7;
  const bfu* Ab = A + (size_t)tm * lda;
  const bfu* Bb = Bt + (size_t)tn * ldb;

  int sr = t >> 2, scc = (t & 3) ^ ((t >> 3) & 3);
  auto stage_half = [&](const bfu* src, int ld, int ldsOfs, int kcol0){
    gld_lds16(src + (size_t)sr * ld + kcol0 + scc * 8,
              lds + ldsOfs + (wave << 10), lane);
  };
  auto stage_tile = [&](int bufOfs, int kc){
    stage_half(Ab, lda, bufOfs, kc);
    stage_half(Ab + (size_t)128 * lda, lda, bufOfs + 8192, kc);
    stage_half(Bb, ldb, bufOfs + 16384, kc);
  };
  int swz = ((lane >> 4) ^ ((lane >> 1) & 3)) << 4;

  f4v acc[4][4];
  f4v zz = {0.f, 0.f, 0.f, 0.f};
  #pragma unroll
  for (int m = 0; m < 4; ++m)
    #pragma unroll
    for (int n = 0; n < 4; ++n) acc[m][n] = zz;

  int nt = K >> 5;
  stage_tile(0, 0);
  stage_tile(24576, 32);
  __builtin_amdgcn_sched_barrier(0);
  asm volatile("s_waitcnt vmcnt(3)" ::: "memory");
  __builtin_amdgcn_sched_barrier(0);
  __builtin_amdgcn_s_barrier();
  __builtin_amdgcn_sched_barrier(0);

  int cbOfs = 0, n1Ofs = 24576, n2Ofs = 49152;
  #pragma unroll 1
  for (int tt = 0; tt < nt; ++tt){
    bool deep = (tt + 2 < nt);
    if (deep) stage_tile(n2Ofs, (tt + 2) << 5);
    s8v af[4], bf[4];
    #pragma unroll
    for (int m = 0; m < 4; ++m)
      af[m] = *(const s8v*)(lds + cbOfs + ((wr * 64 + m * 16 + (lane & 15)) << 6) + swz);
    #pragma unroll
    for (int n = 0; n < 4; ++n)
      bf[n] = *(const s8v*)(lds + cbOfs + 16384 + ((wc * 64 + n * 16 + (lane & 15)) << 6) + swz);
    __builtin_amdgcn_s_setprio(1);
    #pragma unroll
    for (int n = 0; n < 4; ++n)
      #pragma unroll
      for (int m = 0; m < 4; ++m)
        acc[m][n] = MFMA16(af[m], bf[n], acc[m][n], 0, 0, 0);
    __builtin_amdgcn_s_setprio(0);
    __builtin_amdgcn_sched_barrier(0);
    if (deep) { asm volatile("s_waitcnt vmcnt(3)" ::: "memory"); }
    else      { asm volatile("s_waitcnt vmcnt(0)" ::: "memory"); }
    __builtin_amdgcn_sched_barrier(0);
    __builtin_amdgcn_s_barrier();
    __builtin_amdgcn_sched_barrier(0);
    int tmp = cbOfs; cbOfs = n1Ofs; n1Ofs = n2Ofs; n2Ofs = tmp;
  }

  int r0 = (lane >> 4) << 2;
  if (MODE == 0){
    float* rsl = (float*)lds;
    if (t < 256) rsl[t] = rsv[tm + t];
    __syncthreads();
    #pragma unroll
    for (int m = 0; m < 4; ++m)
      #pragma unroll
      for (int n = 0; n < 4; ++n)
        #pragma unroll
        for (int r = 0; r < 4; ++r){
          int rl = wr * 64 + m * 16 + r0 + r;
          size_t rg = (size_t)(tm + rl);
          int cg = tn + wc * 64 + n * 16 + (lane & 15);
          outF[rg * N + cg] = acc[m][n][r] * rsl[rl];
        }
  } else {
    bfu* op; int ldo, cofs;
    if (tn < 4096){ op = outZ; ldo = 4096; cofs = 0; }
    else          { op = outX; ldo = kXBC; cofs = 4096; }
    #pragma unroll
    for (int h = 0; h < 2; ++h){
      __syncthreads();
      if ((wr >> 1) == h){
        #pragma unroll
        for (int m = 0; m < 4; ++m)
          #pragma unroll
          for (int n = 0; n < 4; ++n){
            int col = wc * 64 + n * 16 + (lane & 15);
            int cs = col >> 3, cl = col & 7;
            #pragma unroll
            for (int r = 0; r < 4; ++r){
              int row = (wr & 1) * 64 + m * 16 + r0 + r;   // local 0..127
              *(bfu*)(lds + row * 256 + ((cs ^ (row & 7)) << 4) + cl * 2) = f2bf(acc[m][n][r]);
            }
          }
      }
      __syncthreads();
      int row = t >> 2;                  // 0..127
      bfu* baseo = op + (size_t)(tm + h * 128 + row) * ldo + (tn - cofs);
      #pragma unroll
      for (int i = 0; i < 4; ++i){
        int g = (t & 3) * 4 + i;         // 16 granules of 16B per 256B row
        int cg = tn + g * 8;
        if (cg < kDP){
          uint4 v = *(const uint4*)(lds + row * 256 + ((g ^ (row & 7)) << 4));
          *(uint4*)(baseo + g * 8) = v;
        }
      }
    }
  }
}

// ---------------- causal depthwise conv4 + bias + SiLU; emits xT, B, BT, C ----------------
__global__ __launch_bounds__(256) void k_conv(const bfu* __restrict__ xbc, const float* __restrict__ cw,
    const float* __restrict__ cb, bfu* __restrict__ xT,
    bfu* __restrict__ B16o, bfu* __restrict__ BTo, bfu* __restrict__ C16o){
  int cht = blockIdx.x;                 // 0..65 channel tile (over CONV_DIM)
  int lt = blockIdx.y;                  // 0..127 seq tile over b*l
  int b = lt >> 6;
  int l0 = (lt & 63) << 6;
  int t = threadIdx.x;
  __shared__ float w[256];
  __shared__ float bias[64];
  __shared__ bfu in16[67][66];
  __shared__ bfu out16[64][66];
  if (t < 64) bias[t] = cb[cht * 64 + t];
  w[t] = cw[cht * 256 + t];
  int chbase = cht * 64;
  for (int i = t; i < 67 * 64; i += 256){
    int rrow = i >> 6, cc = i & 63;
    int l = l0 + rrow - 3;
    bfu hv = 0;
    if (l >= 0) hv = xbc[((size_t)b * kSEQ + l) * kXBC + chbase + cc];
    in16[rrow][cc] = hv;
  }
  __syncthreads();
  for (int i = t; i < 4096; i += 256){
    int lr = i >> 6, cc = i & 63;
    float acc = bias[cc];
    #pragma unroll
    for (int j = 0; j < 4; ++j)
      acc += bf2f(in16[lr + j][cc]) * w[cc * 4 + j];
    float sv = acc / (1.f + __expf(-acc));
    out16[lr][cc] = f2bf(sv);
  }
  __syncthreads();
  // row-major outputs: B and C only
  if (chbase >= 4096){
    for (int i = t; i < 4096; i += 256){
      int lr = i >> 6, cc = i & 63;
      size_t row = (size_t)b * kSEQ + l0 + lr;
      int ch = chbase + cc;
      bfu v = out16[lr][cc];
      if (ch < 4096 + kDS) B16o[row * kDS + (ch - 4096)] = v;
      else                 C16o[row * kDS + (ch - 4096 - kDS)] = v;
    }
  }
  // transposed outputs: x -> xT, B -> BT
  if (chbase < 4096 + kDS){
    for (int i = t; i < 4096; i += 256){
      int cc = i >> 6, lr = i & 63;
      int ch = chbase + cc;
      int lg = l0 + lr;
      bfu v = out16[lr][cc];
      if (ch < 4096){
        int hh = ch >> 7, p = ch & 127;
        xT[(((size_t)b * kNH + hh) * kHD + p) * kSEQ + lg] = v;
      } else if (ch < 4096 + kDS){
        BTo[((size_t)b * kDS + (ch - 4096)) * kSEQ + lg] = v;
      }
    }
  }
}

// ---------------- dt = softplus(raw + bias); dA = -exp(A_log)*dt; per-chunk inclusive cumsum ----------------
__global__ __launch_bounds__(256) void k_dtscan(const bfu* __restrict__ xbc, const float* __restrict__ dt_bias,
    const float* __restrict__ A_log, float* __restrict__ dtf, float* __restrict__ acum){
  int bi = blockIdx.x;                  // ((b*16+c)*32+h)
  int h = bi & 31, c = (bi >> 5) & 15, b = bi >> 9;
  int t = threadIdx.x;
  size_t row = (size_t)b * kSEQ + c * kCH + t;
  float draw = bf2f(xbc[row * kXBC + kCV + h]) + dt_bias[h];
  float dt = (draw > 20.f) ? draw : log1pf(__expf(draw));
  dtf[row * kNH + h] = dt;
  float dA = -__expf(A_log[h]) * dt;
  __shared__ float s[256];
  s[t] = dA;
  __syncthreads();
  #pragma unroll
  for (int off = 1; off < 256; off <<= 1){
    float v = (t >= off) ? s[t - off] : 0.f;
    __syncthreads();
    s[t] += v;
    __syncthreads();
  }
  acum[(size_t)bi * 256 + t] = s[t];
}

// ---------------- per-chunk local states[p][n] = sum_l Xt[p][l] * B[l][n]*dt[l]*exp(Atot-Acum[l]) ----------------
__global__ __launch_bounds__(256) void k_states(const bfu* __restrict__ xT, const bfu* __restrict__ BT,
    const float* __restrict__ dtf, const float* __restrict__ acum, bfu* __restrict__ states){
  int bi = blockIdx.x;
  int h = bi & 31, c = (bi >> 5) & 15, b = bi >> 9;
  int t = threadIdx.x, lane = t & 63, wave = t >> 6;
  int wr = wave >> 1, wc = wave & 1;
  __shared__ uint4 ldsX4[1024];         // [128 p][64 l] bf16
  __shared__ uint4 ldsB4[512];          // [64 n][64 l] bf16 (scaled)
  __shared__ float dsv[256];
  char* ldsX = (char*)ldsX4;
  char* ldsB = (char*)ldsB4;
  float Atot = acum[(size_t)bi * 256 + 255];
  {
    size_t row = (size_t)b * kSEQ + c * kCH + t;
    dsv[t] = dtf[row * kNH + h] * __expf(Atot - acum[(size_t)bi * 256 + t]);
  }
  f4v zz = {0.f, 0.f, 0.f, 0.f};
  f4v acc[4][2];
  #pragma unroll
  for (int m = 0; m < 4; ++m){ acc[m][0] = zz; acc[m][1] = zz; }
  const bfu* xTp = xT + ((size_t)b * kNH + h) * kHD * kSEQ + c * kCH;
  const bfu* BTp = BT + (size_t)b * kDS * kSEQ + c * kCH;
  __syncthreads();
  for (int kb = 0; kb < 4; ++kb){
    #pragma unroll
    for (int it = 0; it < 4; ++it){
      int s = it * 256 + t;
      int row = s >> 3;
      int srcslot = (s & 7) ^ (row & 7);
      gld_lds16(xTp + (size_t)row * kSEQ + kb * 64 + srcslot * 8,
                ldsX + it * 4096 + wave * 1024, lane);
    }
    #pragma unroll
    for (int it = 0; it < 2; ++it){
      int cidx = it * 256 + t;
      int row = cidx >> 3, slot = cidx & 7;
      uint4 v = *(const uint4*)(BTp + (size_t)row * kSEQ + kb * 64 + slot * 8);
      bfu* hp = (bfu*)&v;
      #pragma unroll
      for (int j = 0; j < 8; ++j)
        hp[j] = f2bf(bf2f(hp[j]) * dsv[kb * 64 + slot * 8 + j]);
      *(uint4*)(ldsB + (((row << 3) + (slot ^ (row & 7))) << 4)) = v;
    }
    __syncthreads();
    s8v af[4][2], bb[2][2];
    #pragma unroll
    for (int m = 0; m < 4; ++m){
      af[m][0] = frag_ld(ldsX, wr * 64 + m * 16, 0, lane);
      af[m][1] = frag_ld(ldsX, wr * 64 + m * 16, 1, lane);
    }
    #pragma unroll
    for (int nf = 0; nf < 2; ++nf){
      bb[nf][0] = frag_ld(ldsB, wc * 32 + nf * 16, 0, lane);
      bb[nf][1] = frag_ld(ldsB, wc * 32 + nf * 16, 1, lane);
    }
    #pragma unroll
    for (int kh = 0; kh < 2; ++kh)
      #pragma unroll
      for (int m = 0; m < 4; ++m)
        #pragma unroll
        for (int nf = 0; nf < 2; ++nf)
          acc[m][nf] = MFMA16(af[m][kh], bb[nf][kh], acc[m][nf], 0, 0, 0);
    __syncthreads();
  }
  bfu* sp = states + (size_t)bi * 8192;
  int r0 = (lane >> 4) << 2;
  #pragma unroll
  for (int m = 0; m < 4; ++m)
    #pragma unroll
    for (int nf = 0; nf < 2; ++nf)
      #pragma unroll
      for (int r = 0; r < 4; ++r){
        int p = wr * 64 + m * 16 + r0 + r;
        int n = wc * 32 + nf * 16 + (lane & 15);
        sp[p * 64 + n] = f2bf(acc[m][nf][r]);
      }
}

// ---------------- inter-chunk state recurrence (in-place; split over 4 j-groups) ----------------
__global__ __launch_bounds__(256) void k_scan(bfu* __restrict__ st, const float* __restrict__ acum){
  int bh = blockIdx.x >> 2;             // 0..63  (b*32+h)
  int jg = blockIdx.x & 3;              // 0..3
  int b = bh >> 5, h = bh & 31;
  int t = threadIdx.x;
  float run[8];
  #pragma unroll
  for (int j = 0; j < 8; ++j) run[j] = 0.f;
  for (int c = 0; c < 16; ++c){
    size_t bi = (size_t)((b * 16 + c) * 32 + h);
    float eT = __expf(acum[bi * 256 + 255]);
    size_t base = bi * 8192 + (size_t)jg * 2048;
    #pragma unroll
    for (int j = 0; j < 8; ++j){
      size_t idx = base + j * 256 + t;
      float sl = bf2f(st[idx]);
      st[idx] = f2bf(run[j]);
      run[j] = run[j] * eT + sl;
    }
  }
}

// ---------------- Y = (P + D*I)X + Y_off, * silu(z) -> y16; merged p-halves ----------------
// One 512-thread block per bi. Waves: rw = wave&3 (PV row-group of 64 rows),
// pg = wave>>2 (p-half). P [256][64] is ph-independent: per s-block each wave
// computes a 32-row slice of P ONCE into shared ldsP (halves the old sv+exp
// work), then each wave does PV for its (rw, pg) quadrant.
__global__ __launch_bounds__(512, 2) void k_y(
    const bfu* __restrict__ xT, const bfu* __restrict__ Bm, const bfu* __restrict__ Cm,
    const bfu* __restrict__ SIs, const float* __restrict__ dtf, const float* __restrict__ acum,
    const bfu* __restrict__ z16, const float* __restrict__ Dp,
    bfu* __restrict__ y16)
{
  int bi = blockIdx.x;
  int h = bi & 31, c = (bi >> 5) & 15, b = bi >> 9;
  int t = threadIdx.x, lane = t & 63, wave = t >> 6;
  int rw = wave & 3;                    // PV row-group (64 rows)
  int pg = wave >> 2;                   // p-half (64 cols of head dim)
  int tl = rw * 64 + lane;              // thread index within pg-group (0..255)
  __shared__ uint4 ldsP4[2048];         // P [256][64] bf16 = 32KB (swizzled); reused as Y restage
  __shared__ uint4 ldsT4[1024];         // per-pg [64][64] bf16 tile (SI then X), 2 x 8KB
  __shared__ float acumS[256];
  __shared__ float dtS[256];
  char* ldsP = (char*)ldsP4;
  char* ldsT = ((char*)ldsT4) + pg * 8192;
  size_t rowbase = (size_t)b * kSEQ + c * kCH;
  if (t < 256){
    acumS[t] = acum[(size_t)bi * 256 + t];
    dtS[t] = dtf[(rowbase + t) * kNH + h];
  }
  // stage SI tile for this pg (4 waves x 2KB, swizzled direct write)
  const bfu* SIp = SIs + (size_t)bi * 8192 + (size_t)pg * 4096;  // [64 p][64 n] bf16
  #pragma unroll
  for (int it = 0; it < 2; ++it){
    int cidx = it * 256 + tl;
    int row = cidx >> 3, slot = cidx & 7;
    uint4 v = *(const uint4*)(SIp + row * 64 + slot * 8);
    *(uint4*)(ldsT + (((row << 3) + (slot ^ (row & 7))) << 4)) = v;
  }
  const bfu* Cp = Cm + rowbase * kDS;
  s8v cfP[4][2];                        // C-frags for PV/acc-init rows rw*64..
  #pragma unroll
  for (int m = 0; m < 4; ++m){
    cfP[m][0] = *(const s8v*)(Cp + (size_t)(rw * 64 + m * 16 + (lane & 15)) * kDS + ((lane >> 4) << 3));
    cfP[m][1] = *(const s8v*)(Cp + (size_t)(rw * 64 + m * 16 + (lane & 15)) * kDS + 32 + ((lane >> 4) << 3));
  }
  s8v cfS[2][2];                        // C-frags for sv rows wave*32..
  #pragma unroll
  for (int m = 0; m < 2; ++m){
    cfS[m][0] = *(const s8v*)(Cp + (size_t)(wave * 32 + m * 16 + (lane & 15)) * kDS + ((lane >> 4) << 3));
    cfS[m][1] = *(const s8v*)(Cp + (size_t)(wave * 32 + m * 16 + (lane & 15)) * kDS + 32 + ((lane >> 4) << 3));
  }
  __syncthreads();
  float ArowP[16];
  #pragma unroll
  for (int m = 0; m < 4; ++m)
    #pragma unroll
    for (int r = 0; r < 4; ++r)
      ArowP[m * 4 + r] = acumS[rw * 64 + m * 16 + ((lane >> 4) << 2) + r];
  float ArowS[8];
  #pragma unroll
  for (int m = 0; m < 2; ++m)
    #pragma unroll
    for (int r = 0; r < 4; ++r)
      ArowS[m * 4 + r] = acumS[wave * 32 + m * 16 + ((lane >> 4) << 2) + r];
  f4v acc[4][4];
  {
    s8v bfo[4][2];
    #pragma unroll
    for (int pf = 0; pf < 4; ++pf){
      bfo[pf][0] = frag_ld(ldsT, pf << 4, 0, lane);
      bfo[pf][1] = frag_ld(ldsT, pf << 4, 1, lane);
    }
    f4v zz = {0.f, 0.f, 0.f, 0.f};
    #pragma unroll
    for (int m = 0; m < 4; ++m)
      #pragma unroll
      for (int pf = 0; pf < 4; ++pf){
        f4v v = zz;
        v = MFMA16(cfP[m][0], bfo[pf][0], v, 0, 0, 0);
        v = MFMA16(cfP[m][1], bfo[pf][1], v, 0, 0, 0);
        #pragma unroll
        for (int r = 0; r < 4; ++r) v[r] *= __expf(ArowP[m * 4 + r]);
        acc[m][pf] = v;
      }
  }
  float Dh = Dp[h];
  const bfu* Bp = Bm + rowbase * kDS;
  const bfu* xTp = xT + (((size_t)b * kNH + h) * kHD + pg * 64) * kSEQ + c * kCH;
  #pragma unroll 1
  for (int sb = 0; sb < 4; ++sb){
    __syncthreads();                    // prev PV reads of ldsT/ldsP done
    // stage X(sb) tile for this pg (4 waves x 2KB, pre-swizzled source)
    #pragma unroll
    for (int it = 0; it < 2; ++it){
      int s = it * 256 + tl;
      int row = s >> 3;
      int srcslot = (s & 7) ^ (row & 7);
      gld_lds16(xTp + (size_t)row * kSEQ + sb * 64 + srcslot * 8,
                ldsT + it * 4096 + rw * 1024, lane);
    }
    // sv for P rows wave*32..+32 (computed ONCE; ph-independent)
    f4v sv[2][4];
    {
      s8v bsf[4][2];
      #pragma unroll
      for (int sf = 0; sf < 4; ++sf){
        bsf[sf][0] = *(const s8v*)(Bp + (size_t)(sb * 64 + sf * 16 + (lane & 15)) * kDS + ((lane >> 4) << 3));
        bsf[sf][1] = *(const s8v*)(Bp + (size_t)(sb * 64 + sf * 16 + (lane & 15)) * kDS + 32 + ((lane >> 4) << 3));
      }
      f4v zz = {0.f, 0.f, 0.f, 0.f};
      #pragma unroll
      for (int m = 0; m < 2; ++m)
        #pragma unroll
        for (int sf = 0; sf < 4; ++sf){
          f4v v = zz;
          v = MFMA16(cfS[m][0], bsf[sf][0], v, 0, 0, 0);
          v = MFMA16(cfS[m][1], bsf[sf][1], v, 0, 0, 0);
          sv[m][sf] = v;
        }
    }
    int scb = sb << 6;
    float As[4], dts_[4];
    #pragma unroll
    for (int sf = 0; sf < 4; ++sf){
      As[sf] = acumS[scb + sf * 16 + (lane & 15)];
      dts_[sf] = dtS[scb + sf * 16 + (lane & 15)];
    }
    #pragma unroll
    for (int m = 0; m < 2; ++m)
      #pragma unroll
      for (int sf = 0; sf < 4; ++sf)
        #pragma unroll
        for (int r = 0; r < 4; ++r){
          int pr = wave * 32 + m * 16 + ((lane >> 4) << 2) + r;   // P row 0..255
          int scl = sf * 16 + (lane & 15);
          int d = pr - (scb + scl);
          float pv = 0.f;
          if (d >= 0)
            pv = sv[m][sf][r] * __expf(ArowS[m * 4 + r] - As[sf]) * dts_[sf];
          if (d == 0)
            pv += Dh;                   // D-skip folded into P diagonal
          *(bfu*)(ldsP + pr * 128 + ((((scl >> 3) ^ (pr & 7)) << 3) + (scl & 7)) * 2) = f2bf(pv);
        }
    __syncthreads();                    // P ready + X staged (vmcnt drained)
    s8v xb[4][2];
    #pragma unroll
    for (int pf = 0; pf < 4; ++pf){
      xb[pf][0] = frag_ld(ldsT, pf << 4, 0, lane);
      xb[pf][1] = frag_ld(ldsT, pf << 4, 1, lane);
    }
    #pragma unroll
    for (int m = 0; m < 4; ++m){
      s8v pa0 = frag_ld(ldsP, rw * 64 + m * 16, 0, lane);
      s8v pa1 = frag_ld(ldsP, rw * 64 + m * 16, 1, lane);
      #pragma unroll
      for (int pf = 0; pf < 4; ++pf){
        acc[m][pf] = MFMA16(pa0, xb[pf][0], acc[m][pf], 0, 0, 0);
        acc[m][pf] = MFMA16(pa1, xb[pf][1], acc[m][pf], 0, 0, 0);
      }
    }
  }
  // ---- coalesced gated epilogue: two col-halves through ldsP (32KB each) ----
  char* ldsY = (char*)ldsP4;
  #pragma unroll
  for (int half = 0; half < 2; ++half){
    __syncthreads();
    if (pg == half){
      #pragma unroll
      for (int m = 0; m < 4; ++m)
        #pragma unroll
        for (int pf = 0; pf < 4; ++pf)
          #pragma unroll
          for (int r = 0; r < 4; ++r){
            int rloc = rw * 64 + m * 16 + ((lane >> 4) << 2) + r;
            int col  = (pf << 4) + (lane & 15);
            *(bfu*)(ldsY + rloc * 128 + (((col >> 3) ^ (rloc & 7)) << 4) + (col & 7) * 2) = f2bf(acc[m][pf][r]);
          }
    }
    __syncthreads();
    int cg0 = (h << 7) + (half << 6);
    #pragma unroll
    for (int j = 0; j < 4; ++j){
      int idx = j * 512 + t;            // 0..2047
      int row = idx >> 3, g = idx & 7;
      uint4 yv = *(const uint4*)(ldsY + row * 128 + ((g ^ (row & 7)) << 4));
      size_t rowg = rowbase + row;
      uint4 zv4 = *(const uint4*)(z16 + rowg * kDI + cg0 + g * 8);
      const bfu* yp = (const bfu*)&yv;
      const bfu* zp = (const bfu*)&zv4;
      uint4 outv; bfu* op = (bfu*)&outv;
      #pragma unroll
      for (int e = 0; e < 8; ++e){
        float zv = bf2f(zp[e]);
        float sg = zv / (1.f + __expf(-zv));
        op[e] = f2bf(bf2f(yp[e]) * sg);
      }
      *(uint4*)(y16 + rowg * kLDY + cg0 + g * 8) = outv;
    }
  }
}

// ---------------- RMS factors: rs[row] = rsqrt(mean(y^2)+eps) ----------------
__global__ __launch_bounds__(256) void k_rms(const bfu* __restrict__ y, float* __restrict__ rs){
  int row = blockIdx.x;
  int t = threadIdx.x, lane = t & 63, wave = t >> 6;
  const bfu* yp = y + (size_t)row * kLDY;
  uint4 a = *(const uint4*)(yp + t * 8);
  uint4 b = *(const uint4*)(yp + 2048 + t * 8);
  const bfu* ap = (const bfu*)&a;
  const bfu* bp = (const bfu*)&b;
  float ss = 0.f;
  #pragma unroll
  for (int j = 0; j < 8; ++j){
    float va = bf2f(ap[j]); ss += va * va;
    float vb = bf2f(bp[j]); ss += vb * vb;
  }
  #pragma unroll
  for (int o = 32; o > 0; o >>= 1) ss += __shfl_down(ss, o, 64);
  __shared__ float red[4];
  if (lane == 0) red[wave] = ss;
  __syncthreads();
  if (t == 0){
    float tot = red[0] + red[1] + red[2] + red[3];
    rs[row] = rsqrtf(tot * (1.f / 4096.f) + 1e-5f);
  }
}

extern "C" void kernel_launch(void* const* d_in, const int* in_sizes, int n_in,
                              void* d_out, int out_size, void* d_ws, size_t ws_size,
                              hipStream_t stream){
  (void)in_sizes; (void)n_in; (void)out_size; (void)ws_size;
  const float* u       = (const float*)d_in[0];
  const float* W_in    = (const float*)d_in[1];
  const float* conv_w  = (const float*)d_in[2];
  const float* conv_b  = (const float*)d_in[3];
  const float* dt_bias = (const float*)d_in[4];
  const float* A_log   = (const float*)d_in[5];
  const float* Dp      = (const float*)d_in[6];
  const float* norm_w  = (const float*)d_in[7];
  const float* W_out   = (const float*)d_in[8];
  char* ws = (char*)d_ws;

  // Workspace layout: ~242.8 MB total, with lifetime overlays.
  const size_t o_z    = 0;                                     // z16 [8192][4096] bf16   67.11 MB
  const size_t o_xbc  = o_z   + (size_t)kBL * kDI * 2;         // xbc [8192][4256] bf16   69.73 MB -> y16 [8192][4160] after conv (68.2 MB)
  const size_t o_u16  = o_xbc + (size_t)kBL * kXBC * 2;        // u16 [8192][2048] bf16   33.55 MB -> states + woutT
  const size_t o_xT   = o_u16 + (size_t)kBL * kDM * 2;         // xT slot 67.11 MB (winT [8448][2112] = 35.7 MB lives here until GEMM1 ends)
  const size_t o_B16  = o_xT  + (size_t)kBL * kDI * 2;
  const size_t o_BT   = o_B16 + (size_t)kBL * kDS * 2;
  const size_t o_C16  = o_BT  + (size_t)kBL * kDS * 2;
  const size_t o_dtf  = o_C16 + (size_t)kBL * kDS * 2;
  const size_t o_acum = o_dtf + (size_t)kBL * kNH * 4;
  const size_t o_rs   = o_acum + (size_t)1024 * 256 * 4;       // rs [8192] f32, 32 KB
  // overlays:
  const size_t o_states = o_u16;                               // after GEMM1
  const size_t o_woutT  = o_u16 + (size_t)1024 * 8192 * 2;     // after GEMM1
  const size_t o_winT   = o_xT;                                // before conv
  const size_t o_y16    = o_xbc;                               // after conv+dtscan

  bfu* z16    = (bfu*)(ws + o_z);
  bfu* xbc    = (bfu*)(ws + o_xbc);
  bfu* u16    = (bfu*)(ws + o_u16);
  bfu* xT     = (bfu*)(ws + o_xT);
  bfu* B16    = (bfu*)(ws + o_B16);
  bfu* BT     = (bfu*)(ws + o_BT);
  bfu* C16    = (bfu*)(ws + o_C16);
  float* dtf  = (float*)(ws + o_dtf);
  float* acum = (float*)(ws + o_acum);
  float* rs   = (float*)(ws + o_rs);
  bfu* statesS= (bfu*)(ws + o_states);
  bfu* woutT  = (bfu*)(ws + o_woutT);
  bfu* winT   = (bfu*)(ws + o_winT);
  bfu* y16    = (bfu*)(ws + o_y16);

  // allow 72 KiB dynamic LDS on the big GEMMs (idempotent, capture-safe)
  (void)hipFuncSetAttribute(reinterpret_cast<const void*>(&k_gemm256<2>),
                            hipFuncAttributeMaxDynamicSharedMemorySize, 73728);
  (void)hipFuncSetAttribute(reinterpret_cast<const void*>(&k_gemm256<0>),
                            hipFuncAttributeMaxDynamicSharedMemorySize, 73728);

  // zero the 96 pad rows of winT (rows kDP..kDPpad, width kLDW)
  k_zero<<<(96 * kLDW + 255) / 256, 256, 0, stream>>>(winT + (size_t)kDP * kLDW, 96 * kLDW);
  k_cvt<<<2048, 256, 0, stream>>>(u, u16, kBL * kDM / 8);
  k_transpose<<<dim3(kDP / 32, kDM / 32), dim3(32, 8), 0, stream>>>(W_in, winT, kDM, kDP, nullptr, kLDW);
  k_gemm256<2><<<(kDPpad / 128) * (kBL / 256), 512, 73728, stream>>>(u16, winT, nullptr, z16, xbc, nullptr, kDPpad / 128, kDPpad, kDM, kDM, kLDW);
  k_conv<<<dim3(kCV / 64, kBL / 64), 256, 0, stream>>>(xbc, conv_w, conv_b, xT, B16, BT, C16);
  k_dtscan<<<1024, 256, 0, stream>>>(xbc, dt_bias, A_log, dtf, acum);
  // woutT[n][k] = W_out[k][n] * norm_w[k]  (norm weight folded into weights)
  k_transpose<<<dim3(kDM / 32, kDI / 32), dim3(32, 8), 0, stream>>>(W_out, woutT, kDI, kDM, norm_w, kDI);
  k_states<<<1024, 256, 0, stream>>>(xT, BT, dtf, acum, statesS);
  k_scan<<<256, 256, 0, stream>>>(statesS, acum);
  k_y<<<1024, 512, 0, stream>>>(xT, B16, C16, statesS, dtf, acum, z16, Dp, y16);
  k_rms<<<kBL, 256, 0, stream>>>(y16, rs);
  k_gemm256<0><<<(kDM / 128) * (kBL / 256), 512, 73728, stream>>>(y16, woutT, (float*)d_out, nullptr, nullptr, rs, kDM / 128, kDM, kDI, kLDY, kDI);
}

// Round 16
// 734.776 us; speedup vs baseline: 1.1593x; 1.0075x over previous
//
#include <hip/hip_runtime.h>

typedef short s8v __attribute__((ext_vector_type(8)));
typedef float f4v __attribute__((ext_vector_type(4)));
typedef unsigned short bfu;

#define MFMA16 __builtin_amdgcn_mfma_f32_16x16x32_bf16

constexpr int kSEQ = 4096;
constexpr int kBL  = 8192;   // BATCH*SEQLEN
constexpr int kDM  = 2048;   // D_MODEL
constexpr int kDP  = 8352;   // D_IN_PROJ
constexpr int kDPpad = 8448; // padded to 66*128
constexpr int kDI  = 4096;   // D_INNER
constexpr int kCV  = 4224;   // CONV_DIM
constexpr int kXBC = 4256;   // CONV_DIM + NHEADS (xBC | dt columns)
constexpr int kNH  = 32;
constexpr int kHD  = 128;
constexpr int kDS  = 64;
constexpr int kCH  = 256;    // CHUNK
constexpr int kLDW = 2112;   // winT row stride (breaks 4 KB power-of-2 alias)
constexpr int kLDY = 4160;   // y16 row stride (breaks 8 KB power-of-2 alias)

#if defined(__has_builtin)
#  if __has_builtin(__builtin_amdgcn_global_load_lds)
#    define HAS_GLD 1
#  endif
#endif
#ifndef HAS_GLD
#  define HAS_GLD 0
#endif

// Async 16B global->LDS. LDS dest is wave-uniform base + lane*16 (linear).
__device__ __forceinline__ void gld_lds16(const void* g, void* lbase, int lane){
#if HAS_GLD
  (void)lane;
  __builtin_amdgcn_global_load_lds(
      (const __attribute__((address_space(1))) void*)g,
      (__attribute__((address_space(3))) void*)lbase, 16, 0, 0);
#else
  *(uint4*)((char*)lbase + lane * 16) = *(const uint4*)g;
#endif
}

__device__ __forceinline__ bfu f2bf(float f){
  union { float f; unsigned u; } c; c.f = f;
  return (bfu)((c.u + 0x7fffu + ((c.u >> 16) & 1u)) >> 16);
}
__device__ __forceinline__ float bf2f(bfu s){
  union { unsigned u; float f; } c; c.u = ((unsigned)s) << 16;
  return c.f;
}

// Tiles are [R rows][64 bf16] = [R][8 slots of 16B], slot XOR-swizzled by (row&7).
__device__ __forceinline__ s8v frag_ld(const char* lds, int rowbase, int kh, int lane){
  int r = rowbase + (lane & 15);
  int slot = (kh << 2) + (lane >> 4);
  return *(const s8v*)(lds + (((r << 3) + (slot ^ (r & 7))) << 4));
}

// ---------------- zero fill (bf16 elements) ----------------
__global__ __launch_bounds__(256) void k_zero(bfu* __restrict__ p, int n){
  int i = blockIdx.x * 256 + threadIdx.x;
  if (i < n) p[i] = 0;
}

// ---------------- fp32 -> bf16 convert ----------------
__global__ __launch_bounds__(256) void k_cvt(const float* __restrict__ s, bfu* __restrict__ d, int n8){
  int i = blockIdx.x * 256 + threadIdx.x;
  int stride = gridDim.x * 256;
  for (; i < n8; i += stride){
    const float4* sp = (const float4*)(s + (size_t)i * 8);
    float4 a = sp[0], b = sp[1];
    uint4 pk; bfu* pp = (bfu*)&pk;
    pp[0]=f2bf(a.x); pp[1]=f2bf(a.y); pp[2]=f2bf(a.z); pp[3]=f2bf(a.w);
    pp[4]=f2bf(b.x); pp[5]=f2bf(b.y); pp[6]=f2bf(b.z); pp[7]=f2bf(b.w);
    *(uint4*)(d + (size_t)i * 8) = pk;
  }
}

// ---------------- fp32 [R][C] -> bf16 [C][R] transpose (dst ld = ldo), optional scale ----------------
__global__ __launch_bounds__(256) void k_transpose(const float* __restrict__ src, bfu* __restrict__ dst,
                                                   int R, int C, const float* __restrict__ scale, int ldo){
  __shared__ float tile[32][33];
  int c0 = blockIdx.x * 32, r0 = blockIdx.y * 32;
  int tx = threadIdx.x, ty = threadIdx.y;
  #pragma unroll
  for (int i = ty; i < 32; i += 8){
    int r = r0 + i, cc = c0 + tx;
    tile[i][tx] = (r < R && cc < C) ? src[(size_t)r * C + cc] : 0.f;
  }
  __syncthreads();
  #pragma unroll
  for (int i = ty; i < 32; i += 8){
    int dr = c0 + i, dc = r0 + tx;
    if (dr < C && dc < R){
      float v = tile[tx][i];
      if (scale) v *= scale[dc];
      dst[(size_t)dr * ldo + dc] = f2bf(v);
    }
  }
}

// ============ 256x128 GEMM, 2-blocks/CU, 3-buffer ring, counted vmcnt (r14, frozen) ============
// MODE 0: fp32 output, per-row scale computed from ssq partials (rsqrt of mean square).
template<int MODE>
__global__ __launch_bounds__(512, 4) void k_gemm256(const bfu* __restrict__ A, const bfu* __restrict__ Bt,
                                                    float* __restrict__ outF, bfu* __restrict__ outZ,
                                                    bfu* __restrict__ outX, const float* __restrict__ rsv,
                                                    int tilesN, int N, int K, int lda, int ldb){
  extern __shared__ char lds[];         // 73728 B: 3 bufs x (A 16KB + B 8KB)
  int t = threadIdx.x, lane = t & 63, wave = t >> 6;
  int wr = wave >> 1, wc = wave & 1;    // 4 row-groups x 2 col-groups
  int nwg = gridDim.x;
  int bid = blockIdx.x;
  int cpx = nwg >> 3;
  int wg = (bid & 7) * cpx + (bid >> 3);
  int bandSz = tilesN << 2;
  int band = wg / bandSz;
  int rem  = wg - band * bandSz;
  int tnTile = rem >> 2;
  int tmTile = (band << 2) + (rem & 3);
  int tm = tmTile << 8, tn = tnTile << 7;
  const bfu* Ab = A + (size_t)tm * lda;
  const bfu* Bb = Bt + (size_t)tn * ldb;

  int sr = t >> 2, scc = (t & 3) ^ ((t >> 3) & 3);
  auto stage_half = [&](const bfu* src, int ld, int ldsOfs, int kcol0){
    gld_lds16(src + (size_t)sr * ld + kcol0 + scc * 8,
              lds + ldsOfs + (wave << 10), lane);
  };
  auto stage_tile = [&](int bufOfs, int kc){
    stage_half(Ab, lda, bufOfs, kc);
    stage_half(Ab + (size_t)128 * lda, lda, bufOfs + 8192, kc);
    stage_half(Bb, ldb, bufOfs + 16384, kc);
  };
  int swz = ((lane >> 4) ^ ((lane >> 1) & 3)) << 4;

  f4v acc[4][4];
  f4v zz = {0.f, 0.f, 0.f, 0.f};
  #pragma unroll
  for (int m = 0; m < 4; ++m)
    #pragma unroll
    for (int n = 0; n < 4; ++n) acc[m][n] = zz;

  int nt = K >> 5;
  stage_tile(0, 0);
  stage_tile(24576, 32);
  __builtin_amdgcn_sched_barrier(0);
  asm volatile("s_waitcnt vmcnt(3)" ::: "memory");
  __builtin_amdgcn_sched_barrier(0);
  __builtin_amdgcn_s_barrier();
  __builtin_amdgcn_sched_barrier(0);

  int cbOfs = 0, n1Ofs = 24576, n2Ofs = 49152;
  #pragma unroll 1
  for (int tt = 0; tt < nt; ++tt){
    bool deep = (tt + 2 < nt);
    if (deep) stage_tile(n2Ofs, (tt + 2) << 5);
    s8v af[4], bf[4];
    #pragma unroll
    for (int m = 0; m < 4; ++m)
      af[m] = *(const s8v*)(lds + cbOfs + ((wr * 64 + m * 16 + (lane & 15)) << 6) + swz);
    #pragma unroll
    for (int n = 0; n < 4; ++n)
      bf[n] = *(const s8v*)(lds + cbOfs + 16384 + ((wc * 64 + n * 16 + (lane & 15)) << 6) + swz);
    __builtin_amdgcn_s_setprio(1);
    #pragma unroll
    for (int n = 0; n < 4; ++n)
      #pragma unroll
      for (int m = 0; m < 4; ++m)
        acc[m][n] = MFMA16(af[m], bf[n], acc[m][n], 0, 0, 0);
    __builtin_amdgcn_s_setprio(0);
    __builtin_amdgcn_sched_barrier(0);
    if (deep) { asm volatile("s_waitcnt vmcnt(3)" ::: "memory"); }
    else      { asm volatile("s_waitcnt vmcnt(0)" ::: "memory"); }
    __builtin_amdgcn_sched_barrier(0);
    __builtin_amdgcn_s_barrier();
    __builtin_amdgcn_sched_barrier(0);
    int tmp = cbOfs; cbOfs = n1Ofs; n1Ofs = n2Ofs; n2Ofs = tmp;
  }

  int r0 = (lane >> 4) << 2;
  if (MODE == 0){
    // per-row rs = rsqrt(mean(yg^2)+eps) from 32 per-head partials (deterministic)
    float* rsl = (float*)lds;
    if (t < 256){
      const float4* sp = (const float4*)(rsv + (size_t)(tm + t) * kNH);
      float s = 0.f;
      #pragma unroll
      for (int i = 0; i < 8; ++i){ float4 v = sp[i]; s += (v.x + v.y) + (v.z + v.w); }
      rsl[t] = rsqrtf(s * (1.f / 4096.f) + 1e-5f);
    }
    __syncthreads();
    #pragma unroll
    for (int m = 0; m < 4; ++m)
      #pragma unroll
      for (int n = 0; n < 4; ++n)
        #pragma unroll
        for (int r = 0; r < 4; ++r){
          int rl = wr * 64 + m * 16 + r0 + r;
          size_t rg = (size_t)(tm + rl);
          int cg = tn + wc * 64 + n * 16 + (lane & 15);
          outF[rg * N + cg] = acc[m][n][r] * rsl[rl];
        }
  } else {
    bfu* op; int ldo, cofs;
    if (tn < 4096){ op = outZ; ldo = 4096; cofs = 0; }
    else          { op = outX; ldo = kXBC; cofs = 4096; }
    #pragma unroll
    for (int h = 0; h < 2; ++h){
      __syncthreads();
      if ((wr >> 1) == h){
        #pragma unroll
        for (int m = 0; m < 4; ++m)
          #pragma unroll
          for (int n = 0; n < 4; ++n){
            int col = wc * 64 + n * 16 + (lane & 15);
            int cs = col >> 3, cl = col & 7;
            #pragma unroll
            for (int r = 0; r < 4; ++r){
              int row = (wr & 1) * 64 + m * 16 + r0 + r;   // local 0..127
              *(bfu*)(lds + row * 256 + ((cs ^ (row & 7)) << 4) + cl * 2) = f2bf(acc[m][n][r]);
            }
          }
      }
      __syncthreads();
      int row = t >> 2;                  // 0..127
      bfu* baseo = op + (size_t)(tm + h * 128 + row) * ldo + (tn - cofs);
      #pragma unroll
      for (int i = 0; i < 4; ++i){
        int g = (t & 3) * 4 + i;         // 16 granules of 16B per 256B row
        int cg = tn + g * 8;
        if (cg < kDP){
          uint4 v = *(const uint4*)(lds + row * 256 + ((g ^ (row & 7)) << 4));
          *(uint4*)(baseo + g * 8) = v;
        }
      }
    }
  }
}

// ---------------- causal depthwise conv4 + bias + SiLU; emits xT, B, BT, C ----------------
__global__ __launch_bounds__(256) void k_conv(const bfu* __restrict__ xbc, const float* __restrict__ cw,
    const float* __restrict__ cb, bfu* __restrict__ xT,
    bfu* __restrict__ B16o, bfu* __restrict__ BTo, bfu* __restrict__ C16o){
  int cht = blockIdx.x;                 // 0..65 channel tile (over CONV_DIM)
  int lt = blockIdx.y;                  // 0..127 seq tile over b*l
  int b = lt >> 6;
  int l0 = (lt & 63) << 6;
  int t = threadIdx.x;
  __shared__ float w[256];
  __shared__ float bias[64];
  __shared__ bfu in16[67][66];
  __shared__ bfu out16[64][66];
  if (t < 64) bias[t] = cb[cht * 64 + t];
  w[t] = cw[cht * 256 + t];
  int chbase = cht * 64;
  for (int i = t; i < 67 * 64; i += 256){
    int rrow = i >> 6, cc = i & 63;
    int l = l0 + rrow - 3;
    bfu hv = 0;
    if (l >= 0) hv = xbc[((size_t)b * kSEQ + l) * kXBC + chbase + cc];
    in16[rrow][cc] = hv;
  }
  __syncthreads();
  for (int i = t; i < 4096; i += 256){
    int lr = i >> 6, cc = i & 63;
    float acc = bias[cc];
    #pragma unroll
    for (int j = 0; j < 4; ++j)
      acc += bf2f(in16[lr + j][cc]) * w[cc * 4 + j];
    float sv = acc / (1.f + __expf(-acc));
    out16[lr][cc] = f2bf(sv);
  }
  __syncthreads();
  // row-major outputs: B and C only
  if (chbase >= 4096){
    for (int i = t; i < 4096; i += 256){
      int lr = i >> 6, cc = i & 63;
      size_t row = (size_t)b * kSEQ + l0 + lr;
      int ch = chbase + cc;
      bfu v = out16[lr][cc];
      if (ch < 4096 + kDS) B16o[row * kDS + (ch - 4096)] = v;
      else                 C16o[row * kDS + (ch - 4096 - kDS)] = v;
    }
  }
  // transposed outputs: x -> xT, B -> BT
  if (chbase < 4096 + kDS){
    for (int i = t; i < 4096; i += 256){
      int cc = i >> 6, lr = i & 63;
      int ch = chbase + cc;
      int lg = l0 + lr;
      bfu v = out16[lr][cc];
      if (ch < 4096){
        int hh = ch >> 7, p = ch & 127;
        xT[(((size_t)b * kNH + hh) * kHD + p) * kSEQ + lg] = v;
      } else if (ch < 4096 + kDS){
        BTo[((size_t)b * kDS + (ch - 4096)) * kSEQ + lg] = v;
      }
    }
  }
}

// ---------------- dt = softplus(raw + bias); dA = -exp(A_log)*dt; per-chunk inclusive cumsum ----------------
__global__ __launch_bounds__(256) void k_dtscan(const bfu* __restrict__ xbc, const float* __restrict__ dt_bias,
    const float* __restrict__ A_log, float* __restrict__ dtf, float* __restrict__ acum){
  int bi = blockIdx.x;                  // ((b*16+c)*32+h)
  int h = bi & 31, c = (bi >> 5) & 15, b = bi >> 9;
  int t = threadIdx.x;
  size_t row = (size_t)b * kSEQ + c * kCH + t;
  float draw = bf2f(xbc[row * kXBC + kCV + h]) + dt_bias[h];
  float dt = (draw > 20.f) ? draw : log1pf(__expf(draw));
  dtf[row * kNH + h] = dt;
  float dA = -__expf(A_log[h]) * dt;
  __shared__ float s[256];
  s[t] = dA;
  __syncthreads();
  #pragma unroll
  for (int off = 1; off < 256; off <<= 1){
    float v = (t >= off) ? s[t - off] : 0.f;
    __syncthreads();
    s[t] += v;
    __syncthreads();
  }
  acum[(size_t)bi * 256 + t] = s[t];
}

// ---------------- per-chunk local states[p][n] = sum_l Xt[p][l] * B[l][n]*dt[l]*exp(Atot-Acum[l]) ----------------
__global__ __launch_bounds__(256) void k_states(const bfu* __restrict__ xT, const bfu* __restrict__ BT,
    const float* __restrict__ dtf, const float* __restrict__ acum, bfu* __restrict__ states){
  int bi = blockIdx.x;
  int h = bi & 31, c = (bi >> 5) & 15, b = bi >> 9;
  int t = threadIdx.x, lane = t & 63, wave = t >> 6;
  int wr = wave >> 1, wc = wave & 1;
  __shared__ uint4 ldsX4[1024];         // [128 p][64 l] bf16
  __shared__ uint4 ldsB4[512];          // [64 n][64 l] bf16 (scaled)
  __shared__ float dsv[256];
  char* ldsX = (char*)ldsX4;
  char* ldsB = (char*)ldsB4;
  float Atot = acum[(size_t)bi * 256 + 255];
  {
    size_t row = (size_t)b * kSEQ + c * kCH + t;
    dsv[t] = dtf[row * kNH + h] * __expf(Atot - acum[(size_t)bi * 256 + t]);
  }
  f4v zz = {0.f, 0.f, 0.f, 0.f};
  f4v acc[4][2];
  #pragma unroll
  for (int m = 0; m < 4; ++m){ acc[m][0] = zz; acc[m][1] = zz; }
  const bfu* xTp = xT + ((size_t)b * kNH + h) * kHD * kSEQ + c * kCH;
  const bfu* BTp = BT + (size_t)b * kDS * kSEQ + c * kCH;
  __syncthreads();
  for (int kb = 0; kb < 4; ++kb){
    #pragma unroll
    for (int it = 0; it < 4; ++it){
      int s = it * 256 + t;
      int row = s >> 3;
      int srcslot = (s & 7) ^ (row & 7);
      gld_lds16(xTp + (size_t)row * kSEQ + kb * 64 + srcslot * 8,
                ldsX + it * 4096 + wave * 1024, lane);
    }
    #pragma unroll
    for (int it = 0; it < 2; ++it){
      int cidx = it * 256 + t;
      int row = cidx >> 3, slot = cidx & 7;
      uint4 v = *(const uint4*)(BTp + (size_t)row * kSEQ + kb * 64 + slot * 8);
      bfu* hp = (bfu*)&v;
      #pragma unroll
      for (int j = 0; j < 8; ++j)
        hp[j] = f2bf(bf2f(hp[j]) * dsv[kb * 64 + slot * 8 + j]);
      *(uint4*)(ldsB + (((row << 3) + (slot ^ (row & 7))) << 4)) = v;
    }
    __syncthreads();
    s8v af[4][2], bb[2][2];
    #pragma unroll
    for (int m = 0; m < 4; ++m){
      af[m][0] = frag_ld(ldsX, wr * 64 + m * 16, 0, lane);
      af[m][1] = frag_ld(ldsX, wr * 64 + m * 16, 1, lane);
    }
    #pragma unroll
    for (int nf = 0; nf < 2; ++nf){
      bb[nf][0] = frag_ld(ldsB, wc * 32 + nf * 16, 0, lane);
      bb[nf][1] = frag_ld(ldsB, wc * 32 + nf * 16, 1, lane);
    }
    #pragma unroll
    for (int kh = 0; kh < 2; ++kh)
      #pragma unroll
      for (int m = 0; m < 4; ++m)
        #pragma unroll
        for (int nf = 0; nf < 2; ++nf)
          acc[m][nf] = MFMA16(af[m][kh], bb[nf][kh], acc[m][nf], 0, 0, 0);
    __syncthreads();
  }
  bfu* sp = states + (size_t)bi * 8192;
  int r0 = (lane >> 4) << 2;
  #pragma unroll
  for (int m = 0; m < 4; ++m)
    #pragma unroll
    for (int nf = 0; nf < 2; ++nf)
      #pragma unroll
      for (int r = 0; r < 4; ++r){
        int p = wr * 64 + m * 16 + r0 + r;
        int n = wc * 32 + nf * 16 + (lane & 15);
        sp[p * 64 + n] = f2bf(acc[m][nf][r]);
      }
}

// ---------------- inter-chunk state recurrence (in-place; split over 4 j-groups) ----------------
__global__ __launch_bounds__(256) void k_scan(bfu* __restrict__ st, const float* __restrict__ acum){
  int bh = blockIdx.x >> 2;             // 0..63  (b*32+h)
  int jg = blockIdx.x & 3;              // 0..3
  int b = bh >> 5, h = bh & 31;
  int t = threadIdx.x;
  float run[8];
  #pragma unroll
  for (int j = 0; j < 8; ++j) run[j] = 0.f;
  for (int c = 0; c < 16; ++c){
    size_t bi = (size_t)((b * 16 + c) * 32 + h);
    float eT = __expf(acum[bi * 256 + 255]);
    size_t base = bi * 8192 + (size_t)jg * 2048;
    #pragma unroll
    for (int j = 0; j < 8; ++j){
      size_t idx = base + j * 256 + t;
      float sl = bf2f(st[idx]);
      st[idx] = f2bf(run[j]);
      run[j] = run[j] * eT + sl;
    }
  }
}

// ---------------- Y = (P + D*I)X + Y_off, * silu(z) -> y16; merged p-halves + ssq partials ----------------
__global__ __launch_bounds__(512, 2) void k_y(
    const bfu* __restrict__ xT, const bfu* __restrict__ Bm, const bfu* __restrict__ Cm,
    const bfu* __restrict__ SIs, const float* __restrict__ dtf, const float* __restrict__ acum,
    const bfu* __restrict__ z16, const float* __restrict__ Dp,
    bfu* __restrict__ y16, float* __restrict__ ssq)
{
  int bi = blockIdx.x;
  int h = bi & 31, c = (bi >> 5) & 15, b = bi >> 9;
  int t = threadIdx.x, lane = t & 63, wave = t >> 6;
  int rw = wave & 3;                    // PV row-group (64 rows)
  int pg = wave >> 2;                   // p-half (64 cols of head dim)
  int tl = rw * 64 + lane;              // thread index within pg-group (0..255)
  __shared__ uint4 ldsP4[2048];         // P [256][64] bf16 = 32KB (swizzled); reused as Y restage
  __shared__ uint4 ldsT4[1024];         // per-pg [64][64] bf16 tile (SI then X), 2 x 8KB
  __shared__ float acumS[256];
  __shared__ float dtS[256];
  char* ldsP = (char*)ldsP4;
  char* ldsT = ((char*)ldsT4) + pg * 8192;
  size_t rowbase = (size_t)b * kSEQ + c * kCH;
  if (t < 256){
    acumS[t] = acum[(size_t)bi * 256 + t];
    dtS[t] = dtf[(rowbase + t) * kNH + h];
  }
  // stage SI tile for this pg (4 waves x 2KB, swizzled direct write)
  const bfu* SIp = SIs + (size_t)bi * 8192 + (size_t)pg * 4096;  // [64 p][64 n] bf16
  #pragma unroll
  for (int it = 0; it < 2; ++it){
    int cidx = it * 256 + tl;
    int row = cidx >> 3, slot = cidx & 7;
    uint4 v = *(const uint4*)(SIp + row * 64 + slot * 8);
    *(uint4*)(ldsT + (((row << 3) + (slot ^ (row & 7))) << 4)) = v;
  }
  const bfu* Cp = Cm + rowbase * kDS;
  s8v cfP[4][2];                        // C-frags for PV/acc-init rows rw*64..
  #pragma unroll
  for (int m = 0; m < 4; ++m){
    cfP[m][0] = *(const s8v*)(Cp + (size_t)(rw * 64 + m * 16 + (lane & 15)) * kDS + ((lane >> 4) << 3));
    cfP[m][1] = *(const s8v*)(Cp + (size_t)(rw * 64 + m * 16 + (lane & 15)) * kDS + 32 + ((lane >> 4) << 3));
  }
  s8v cfS[2][2];                        // C-frags for sv rows wave*32..
  #pragma unroll
  for (int m = 0; m < 2; ++m){
    cfS[m][0] = *(const s8v*)(Cp + (size_t)(wave * 32 + m * 16 + (lane & 15)) * kDS + ((lane >> 4) << 3));
    cfS[m][1] = *(const s8v*)(Cp + (size_t)(wave * 32 + m * 16 + (lane & 15)) * kDS + 32 + ((lane >> 4) << 3));
  }
  __syncthreads();
  float ArowP[16];
  #pragma unroll
  for (int m = 0; m < 4; ++m)
    #pragma unroll
    for (int r = 0; r < 4; ++r)
      ArowP[m * 4 + r] = acumS[rw * 64 + m * 16 + ((lane >> 4) << 2) + r];
  float ArowS[8];
  #pragma unroll
  for (int m = 0; m < 2; ++m)
    #pragma unroll
    for (int r = 0; r < 4; ++r)
      ArowS[m * 4 + r] = acumS[wave * 32 + m * 16 + ((lane >> 4) << 2) + r];
  f4v acc[4][4];
  {
    s8v bfo[4][2];
    #pragma unroll
    for (int pf = 0; pf < 4; ++pf){
      bfo[pf][0] = frag_ld(ldsT, pf << 4, 0, lane);
      bfo[pf][1] = frag_ld(ldsT, pf << 4, 1, lane);
    }
    f4v zz = {0.f, 0.f, 0.f, 0.f};
    #pragma unroll
    for (int m = 0; m < 4; ++m)
      #pragma unroll
      for (int pf = 0; pf < 4; ++pf){
        f4v v = zz;
        v = MFMA16(cfP[m][0], bfo[pf][0], v, 0, 0, 0);
        v = MFMA16(cfP[m][1], bfo[pf][1], v, 0, 0, 0);
        #pragma unroll
        for (int r = 0; r < 4; ++r) v[r] *= __expf(ArowP[m * 4 + r]);
        acc[m][pf] = v;
      }
  }
  float Dh = Dp[h];
  const bfu* Bp = Bm + rowbase * kDS;
  const bfu* xTp = xT + (((size_t)b * kNH + h) * kHD + pg * 64) * kSEQ + c * kCH;
  #pragma unroll 1
  for (int sb = 0; sb < 4; ++sb){
    __syncthreads();                    // prev PV reads of ldsT/ldsP done
    #pragma unroll
    for (int it = 0; it < 2; ++it){
      int s = it * 256 + tl;
      int row = s >> 3;
      int srcslot = (s & 7) ^ (row & 7);
      gld_lds16(xTp + (size_t)row * kSEQ + sb * 64 + srcslot * 8,
                ldsT + it * 4096 + rw * 1024, lane);
    }
    f4v sv[2][4];
    {
      s8v bsf[4][2];
      #pragma unroll
      for (int sf = 0; sf < 4; ++sf){
        bsf[sf][0] = *(const s8v*)(Bp + (size_t)(sb * 64 + sf * 16 + (lane & 15)) * kDS + ((lane >> 4) << 3));
        bsf[sf][1] = *(const s8v*)(Bp + (size_t)(sb * 64 + sf * 16 + (lane & 15)) * kDS + 32 + ((lane >> 4) << 3));
      }
      f4v zz = {0.f, 0.f, 0.f, 0.f};
      #pragma unroll
      for (int m = 0; m < 2; ++m)
        #pragma unroll
        for (int sf = 0; sf < 4; ++sf){
          f4v v = zz;
          v = MFMA16(cfS[m][0], bsf[sf][0], v, 0, 0, 0);
          v = MFMA16(cfS[m][1], bsf[sf][1], v, 0, 0, 0);
          sv[m][sf] = v;
        }
    }
    int scb = sb << 6;
    float As[4], dts_[4];
    #pragma unroll
    for (int sf = 0; sf < 4; ++sf){
      As[sf] = acumS[scb + sf * 16 + (lane & 15)];
      dts_[sf] = dtS[scb + sf * 16 + (lane & 15)];
    }
    #pragma unroll
    for (int m = 0; m < 2; ++m)
      #pragma unroll
      for (int sf = 0; sf < 4; ++sf)
        #pragma unroll
        for (int r = 0; r < 4; ++r){
          int pr = wave * 32 + m * 16 + ((lane >> 4) << 2) + r;   // P row 0..255
          int scl = sf * 16 + (lane & 15);
          int d = pr - (scb + scl);
          float pv = 0.f;
          if (d >= 0)
            pv = sv[m][sf][r] * __expf(ArowS[m * 4 + r] - As[sf]) * dts_[sf];
          if (d == 0)
            pv += Dh;                   // D-skip folded into P diagonal
          *(bfu*)(ldsP + pr * 128 + ((((scl >> 3) ^ (pr & 7)) << 3) + (scl & 7)) * 2) = f2bf(pv);
        }
    __syncthreads();                    // P ready + X staged (vmcnt drained)
    s8v xb[4][2];
    #pragma unroll
    for (int pf = 0; pf < 4; ++pf){
      xb[pf][0] = frag_ld(ldsT, pf << 4, 0, lane);
      xb[pf][1] = frag_ld(ldsT, pf << 4, 1, lane);
    }
    #pragma unroll
    for (int m = 0; m < 4; ++m){
      s8v pa0 = frag_ld(ldsP, rw * 64 + m * 16, 0, lane);
      s8v pa1 = frag_ld(ldsP, rw * 64 + m * 16, 1, lane);
      #pragma unroll
      for (int pf = 0; pf < 4; ++pf){
        acc[m][pf] = MFMA16(pa0, xb[pf][0], acc[m][pf], 0, 0, 0);
        acc[m][pf] = MFMA16(pa1, xb[pf][1], acc[m][pf], 0, 0, 0);
      }
    }
  }
  // ---- coalesced gated epilogue: two col-halves through ldsP; ssq partials ----
  char* ldsY = (char*)ldsP4;
  float myss[4] = {0.f, 0.f, 0.f, 0.f};
  #pragma unroll
  for (int half = 0; half < 2; ++half){
    __syncthreads();
    if (pg == half){
      #pragma unroll
      for (int m = 0; m < 4; ++m)
        #pragma unroll
        for (int pf = 0; pf < 4; ++pf)
          #pragma unroll
          for (int r = 0; r < 4; ++r){
            int rloc = rw * 64 + m * 16 + ((lane >> 4) << 2) + r;
            int col  = (pf << 4) + (lane & 15);
            *(bfu*)(ldsY + rloc * 128 + (((col >> 3) ^ (rloc & 7)) << 4) + (col & 7) * 2) = f2bf(acc[m][pf][r]);
          }
    }
    __syncthreads();
    int cg0 = (h << 7) + (half << 6);
    #pragma unroll
    for (int j = 0; j < 4; ++j){
      int idx = j * 512 + t;            // 0..2047
      int row = idx >> 3, g = idx & 7;
      uint4 yv = *(const uint4*)(ldsY + row * 128 + ((g ^ (row & 7)) << 4));
      size_t rowg = rowbase + row;
      uint4 zv4 = *(const uint4*)(z16 + rowg * kDI + cg0 + g * 8);
      const bfu* yp = (const bfu*)&yv;
      const bfu* zp = (const bfu*)&zv4;
      uint4 outv; bfu* op = (bfu*)&outv;
      float ls = 0.f;
      #pragma unroll
      for (int e = 0; e < 8; ++e){
        float zv = bf2f(zp[e]);
        float sg = zv / (1.f + __expf(-zv));
        op[e] = f2bf(bf2f(yp[e]) * sg);
        float gv = bf2f(op[e]);
        ls += gv * gv;
      }
      myss[j] += ls;
      *(uint4*)(y16 + rowg * kLDY + cg0 + g * 8) = outv;
    }
  }
  // reduce 8 lanes per row (t&7 groups share a row), one partial per (row, head)
  #pragma unroll
  for (int j = 0; j < 4; ++j){
    float red = myss[j];
    red += __shfl_down(red, 4, 8);
    red += __shfl_down(red, 2, 8);
    red += __shfl_down(red, 1, 8);
    if ((t & 7) == 0){
      int row = j * 64 + (t >> 3);
      ssq[(rowbase + row) * kNH + h] = red;
    }
  }
}

extern "C" void kernel_launch(void* const* d_in, const int* in_sizes, int n_in,
                              void* d_out, int out_size, void* d_ws, size_t ws_size,
                              hipStream_t stream){
  (void)in_sizes; (void)n_in; (void)out_size; (void)ws_size;
  const float* u       = (const float*)d_in[0];
  const float* W_in    = (const float*)d_in[1];
  const float* conv_w  = (const float*)d_in[2];
  const float* conv_b  = (const float*)d_in[3];
  const float* dt_bias = (const float*)d_in[4];
  const float* A_log   = (const float*)d_in[5];
  const float* Dp      = (const float*)d_in[6];
  const float* norm_w  = (const float*)d_in[7];
  const float* W_out   = (const float*)d_in[8];
  char* ws = (char*)d_ws;

  // Workspace layout: ~243.8 MB total, with lifetime overlays.
  const size_t o_z    = 0;                                     // z16 [8192][4096] bf16   67.11 MB
  const size_t o_xbc  = o_z   + (size_t)kBL * kDI * 2;         // xbc [8192][4256] bf16 -> y16 [8192][4160] after conv
  const size_t o_u16  = o_xbc + (size_t)kBL * kXBC * 2;        // u16 -> states + woutT
  const size_t o_xT   = o_u16 + (size_t)kBL * kDM * 2;         // xT slot (winT lives here until GEMM1 ends)
  const size_t o_B16  = o_xT  + (size_t)kBL * kDI * 2;
  const size_t o_BT   = o_B16 + (size_t)kBL * kDS * 2;
  const size_t o_C16  = o_BT  + (size_t)kBL * kDS * 2;
  const size_t o_dtf  = o_C16 + (size_t)kBL * kDS * 2;
  const size_t o_acum = o_dtf + (size_t)kBL * kNH * 4;
  const size_t o_ssq  = o_acum + (size_t)1024 * 256 * 4;       // ssq [8192][32] f32, 1 MB
  // overlays:
  const size_t o_states = o_u16;                               // after GEMM1
  const size_t o_woutT  = o_u16 + (size_t)1024 * 8192 * 2;     // after GEMM1
  const size_t o_winT   = o_xT;                                // before conv
  const size_t o_y16    = o_xbc;                               // after conv+dtscan

  bfu* z16    = (bfu*)(ws + o_z);
  bfu* xbc    = (bfu*)(ws + o_xbc);
  bfu* u16    = (bfu*)(ws + o_u16);
  bfu* xT     = (bfu*)(ws + o_xT);
  bfu* B16    = (bfu*)(ws + o_B16);
  bfu* BT     = (bfu*)(ws + o_BT);
  bfu* C16    = (bfu*)(ws + o_C16);
  float* dtf  = (float*)(ws + o_dtf);
  float* acum = (float*)(ws + o_acum);
  float* ssq  = (float*)(ws + o_ssq);
  bfu* statesS= (bfu*)(ws + o_states);
  bfu* woutT  = (bfu*)(ws + o_woutT);
  bfu* winT   = (bfu*)(ws + o_winT);
  bfu* y16    = (bfu*)(ws + o_y16);

  // allow 72 KiB dynamic LDS on the big GEMMs (idempotent, capture-safe)
  (void)hipFuncSetAttribute(reinterpret_cast<const void*>(&k_gemm256<2>),
                            hipFuncAttributeMaxDynamicSharedMemorySize, 73728);
  (void)hipFuncSetAttribute(reinterpret_cast<const void*>(&k_gemm256<0>),
                            hipFuncAttributeMaxDynamicSharedMemorySize, 73728);

  // zero the 96 pad rows of winT (rows kDP..kDPpad, width kLDW)
  k_zero<<<(96 * kLDW + 255) / 256, 256, 0, stream>>>(winT + (size_t)kDP * kLDW, 96 * kLDW);
  k_cvt<<<2048, 256, 0, stream>>>(u, u16, kBL * kDM / 8);
  k_transpose<<<dim3(kDP / 32, kDM / 32), dim3(32, 8), 0, stream>>>(W_in, winT, kDM, kDP, nullptr, kLDW);
  k_gemm256<2><<<(kDPpad / 128) * (kBL / 256), 512, 73728, stream>>>(u16, winT, nullptr, z16, xbc, nullptr, kDPpad / 128, kDPpad, kDM, kDM, kLDW);
  k_conv<<<dim3(kCV / 64, kBL / 64), 256, 0, stream>>>(xbc, conv_w, conv_b, xT, B16, BT, C16);
  k_dtscan<<<1024, 256, 0, stream>>>(xbc, dt_bias, A_log, dtf, acum);
  // woutT[n][k] = W_out[k][n] * norm_w[k]  (norm weight folded into weights)
  k_transpose<<<dim3(kDM / 32, kDI / 32), dim3(32, 8), 0, stream>>>(W_out, woutT, kDI, kDM, norm_w, kDI);
  k_states<<<1024, 256, 0, stream>>>(xT, BT, dtf, acum, statesS);
  k_scan<<<256, 256, 0, stream>>>(statesS, acum);
  k_y<<<1024, 512, 0, stream>>>(xT, B16, C16, statesS, dtf, acum, z16, Dp, y16, ssq);
  k_gemm256<0><<<(kDM / 128) * (kBL / 256), 512, 73728, stream>>>(y16, woutT, (float*)d_out, nullptr, nullptr, ssq, kDM / 128, kDM, kDI, kLDY, kDI);
}

// Round 17
// 717.389 us; speedup vs baseline: 1.1874x; 1.0242x over previous
//
#include <hip/hip_runtime.h>

typedef short s8v __attribute__((ext_vector_type(8)));
typedef float f4v __attribute__((ext_vector_type(4)));
typedef unsigned short bfu;

#define MFMA16 __builtin_amdgcn_mfma_f32_16x16x32_bf16

constexpr int kSEQ = 4096;
constexpr int kBL  = 8192;   // BATCH*SEQLEN
constexpr int kDM  = 2048;   // D_MODEL
constexpr int kDP  = 8352;   // D_IN_PROJ
constexpr int kDPpad = 8448; // padded to 66*128
constexpr int kDI  = 4096;   // D_INNER
constexpr int kCV  = 4224;   // CONV_DIM
constexpr int kXBC = 4256;   // CONV_DIM + NHEADS (xBC | dt columns)
constexpr int kNH  = 32;
constexpr int kHD  = 128;
constexpr int kDS  = 64;
constexpr int kCH  = 256;    // CHUNK
constexpr int kLDW = 2112;   // winT row stride (breaks 4 KB power-of-2 alias)
constexpr int kLDY = 4160;   // y16 row stride (breaks 8 KB power-of-2 alias)

#if defined(__has_builtin)
#  if __has_builtin(__builtin_amdgcn_global_load_lds)
#    define HAS_GLD 1
#  endif
#endif
#ifndef HAS_GLD
#  define HAS_GLD 0
#endif

// Async 16B global->LDS. LDS dest is wave-uniform base + lane*16 (linear).
__device__ __forceinline__ void gld_lds16(const void* g, void* lbase, int lane){
#if HAS_GLD
  (void)lane;
  __builtin_amdgcn_global_load_lds(
      (const __attribute__((address_space(1))) void*)g,
      (__attribute__((address_space(3))) void*)lbase, 16, 0, 0);
#else
  *(uint4*)((char*)lbase + lane * 16) = *(const uint4*)g;
#endif
}

__device__ __forceinline__ bfu f2bf(float f){
  union { float f; unsigned u; } c; c.f = f;
  return (bfu)((c.u + 0x7fffu + ((c.u >> 16) & 1u)) >> 16);
}
__device__ __forceinline__ float bf2f(bfu s){
  union { unsigned u; float f; } c; c.u = ((unsigned)s) << 16;
  return c.f;
}

// Tiles are [R rows][64 bf16] = [R][8 slots of 16B], slot XOR-swizzled by (row&7).
__device__ __forceinline__ s8v frag_ld(const char* lds, int rowbase, int kh, int lane){
  int r = rowbase + (lane & 15);
  int slot = (kh << 2) + (lane >> 4);
  return *(const s8v*)(lds + (((r << 3) + (slot ^ (r & 7))) << 4));
}

// ---------------- zero fill (bf16 elements) ----------------
__global__ __launch_bounds__(256) void k_zero(bfu* __restrict__ p, int n){
  int i = blockIdx.x * 256 + threadIdx.x;
  if (i < n) p[i] = 0;
}

// ---------------- fp32 -> bf16 convert ----------------
__global__ __launch_bounds__(256) void k_cvt(const float* __restrict__ s, bfu* __restrict__ d, int n8){
  int i = blockIdx.x * 256 + threadIdx.x;
  int stride = gridDim.x * 256;
  for (; i < n8; i += stride){
    const float4* sp = (const float4*)(s + (size_t)i * 8);
    float4 a = sp[0], b = sp[1];
    uint4 pk; bfu* pp = (bfu*)&pk;
    pp[0]=f2bf(a.x); pp[1]=f2bf(a.y); pp[2]=f2bf(a.z); pp[3]=f2bf(a.w);
    pp[4]=f2bf(b.x); pp[5]=f2bf(b.y); pp[6]=f2bf(b.z); pp[7]=f2bf(b.w);
    *(uint4*)(d + (size_t)i * 8) = pk;
  }
}

// ---------------- fp32 [R][C] -> bf16 [C][R] transpose (dst ld = ldo), optional scale ----------------
__global__ __launch_bounds__(256) void k_transpose(const float* __restrict__ src, bfu* __restrict__ dst,
                                                   int R, int C, const float* __restrict__ scale, int ldo){
  __shared__ float tile[32][33];
  int c0 = blockIdx.x * 32, r0 = blockIdx.y * 32;
  int tx = threadIdx.x, ty = threadIdx.y;
  #pragma unroll
  for (int i = ty; i < 32; i += 8){
    int r = r0 + i, cc = c0 + tx;
    tile[i][tx] = (r < R && cc < C) ? src[(size_t)r * C + cc] : 0.f;
  }
  __syncthreads();
  #pragma unroll
  for (int i = ty; i < 32; i += 8){
    int dr = c0 + i, dc = r0 + tx;
    if (dr < C && dc < R){
      float v = tile[tx][i];
      if (scale) v *= scale[dc];
      dst[(size_t)dr * ldo + dc] = f2bf(v);
    }
  }
}

// ============ 256x128 GEMM, 2-blocks/CU, 3-buffer ring, counted vmcnt (r14, frozen) ============
// MODE 0: fp32 output, per-row scale computed from ssq partials (rsqrt of mean square).
template<int MODE>
__global__ __launch_bounds__(512, 4) void k_gemm256(const bfu* __restrict__ A, const bfu* __restrict__ Bt,
                                                    float* __restrict__ outF, bfu* __restrict__ outZ,
                                                    bfu* __restrict__ outX, const float* __restrict__ rsv,
                                                    int tilesN, int N, int K, int lda, int ldb){
  extern __shared__ char lds[];         // 73728 B: 3 bufs x (A 16KB + B 8KB)
  int t = threadIdx.x, lane = t & 63, wave = t >> 6;
  int wr = wave >> 1, wc = wave & 1;    // 4 row-groups x 2 col-groups
  int nwg = gridDim.x;
  int bid = blockIdx.x;
  int cpx = nwg >> 3;
  int wg = (bid & 7) * cpx + (bid >> 3);
  int bandSz = tilesN << 2;
  int band = wg / bandSz;
  int rem  = wg - band * bandSz;
  int tnTile = rem >> 2;
  int tmTile = (band << 2) + (rem & 3);
  int tm = tmTile << 8, tn = tnTile << 7;
  const bfu* Ab = A + (size_t)tm * lda;
  const bfu* Bb = Bt + (size_t)tn * ldb;

  int sr = t >> 2, scc = (t & 3) ^ ((t >> 3) & 3);
  auto stage_half = [&](const bfu* src, int ld, int ldsOfs, int kcol0){
    gld_lds16(src + (size_t)sr * ld + kcol0 + scc * 8,
              lds + ldsOfs + (wave << 10), lane);
  };
  auto stage_tile = [&](int bufOfs, int kc){
    stage_half(Ab, lda, bufOfs, kc);
    stage_half(Ab + (size_t)128 * lda, lda, bufOfs + 8192, kc);
    stage_half(Bb, ldb, bufOfs + 16384, kc);
  };
  int swz = ((lane >> 4) ^ ((lane >> 1) & 3)) << 4;

  f4v acc[4][4];
  f4v zz = {0.f, 0.f, 0.f, 0.f};
  #pragma unroll
  for (int m = 0; m < 4; ++m)
    #pragma unroll
    for (int n = 0; n < 4; ++n) acc[m][n] = zz;

  int nt = K >> 5;
  stage_tile(0, 0);
  stage_tile(24576, 32);
  __builtin_amdgcn_sched_barrier(0);
  asm volatile("s_waitcnt vmcnt(3)" ::: "memory");
  __builtin_amdgcn_sched_barrier(0);
  __builtin_amdgcn_s_barrier();
  __builtin_amdgcn_sched_barrier(0);

  int cbOfs = 0, n1Ofs = 24576, n2Ofs = 49152;
  #pragma unroll 1
  for (int tt = 0; tt < nt; ++tt){
    bool deep = (tt + 2 < nt);
    if (deep) stage_tile(n2Ofs, (tt + 2) << 5);
    s8v af[4], bf[4];
    #pragma unroll
    for (int m = 0; m < 4; ++m)
      af[m] = *(const s8v*)(lds + cbOfs + ((wr * 64 + m * 16 + (lane & 15)) << 6) + swz);
    #pragma unroll
    for (int n = 0; n < 4; ++n)
      bf[n] = *(const s8v*)(lds + cbOfs + 16384 + ((wc * 64 + n * 16 + (lane & 15)) << 6) + swz);
    __builtin_amdgcn_s_setprio(1);
    #pragma unroll
    for (int n = 0; n < 4; ++n)
      #pragma unroll
      for (int m = 0; m < 4; ++m)
        acc[m][n] = MFMA16(af[m], bf[n], acc[m][n], 0, 0, 0);
    __builtin_amdgcn_s_setprio(0);
    __builtin_amdgcn_sched_barrier(0);
    if (deep) { asm volatile("s_waitcnt vmcnt(3)" ::: "memory"); }
    else      { asm volatile("s_waitcnt vmcnt(0)" ::: "memory"); }
    __builtin_amdgcn_sched_barrier(0);
    __builtin_amdgcn_s_barrier();
    __builtin_amdgcn_sched_barrier(0);
    int tmp = cbOfs; cbOfs = n1Ofs; n1Ofs = n2Ofs; n2Ofs = tmp;
  }

  int r0 = (lane >> 4) << 2;
  if (MODE == 0){
    // per-row rs = rsqrt(mean(yg^2)+eps) from 32 per-head partials (deterministic)
    float* rsl = (float*)lds;
    if (t < 256){
      const float4* sp = (const float4*)(rsv + (size_t)(tm + t) * kNH);
      float s = 0.f;
      #pragma unroll
      for (int i = 0; i < 8; ++i){ float4 v = sp[i]; s += (v.x + v.y) + (v.z + v.w); }
      rsl[t] = rsqrtf(s * (1.f / 4096.f) + 1e-5f);
    }
    __syncthreads();
    #pragma unroll
    for (int m = 0; m < 4; ++m)
      #pragma unroll
      for (int n = 0; n < 4; ++n)
        #pragma unroll
        for (int r = 0; r < 4; ++r){
          int rl = wr * 64 + m * 16 + r0 + r;
          size_t rg = (size_t)(tm + rl);
          int cg = tn + wc * 64 + n * 16 + (lane & 15);
          outF[rg * N + cg] = acc[m][n][r] * rsl[rl];
        }
  } else {
    bfu* op; int ldo, cofs;
    if (tn < 4096){ op = outZ; ldo = 4096; cofs = 0; }
    else          { op = outX; ldo = kXBC; cofs = 4096; }
    #pragma unroll
    for (int h = 0; h < 2; ++h){
      __syncthreads();
      if ((wr >> 1) == h){
        #pragma unroll
        for (int m = 0; m < 4; ++m)
          #pragma unroll
          for (int n = 0; n < 4; ++n){
            int col = wc * 64 + n * 16 + (lane & 15);
            int cs = col >> 3, cl = col & 7;
            #pragma unroll
            for (int r = 0; r < 4; ++r){
              int row = (wr & 1) * 64 + m * 16 + r0 + r;   // local 0..127
              *(bfu*)(lds + row * 256 + ((cs ^ (row & 7)) << 4) + cl * 2) = f2bf(acc[m][n][r]);
            }
          }
      }
      __syncthreads();
      int row = t >> 2;                  // 0..127
      bfu* baseo = op + (size_t)(tm + h * 128 + row) * ldo + (tn - cofs);
      #pragma unroll
      for (int i = 0; i < 4; ++i){
        int g = (t & 3) * 4 + i;         // 16 granules of 16B per 256B row
        int cg = tn + g * 8;
        if (cg < kDP){
          uint4 v = *(const uint4*)(lds + row * 256 + ((g ^ (row & 7)) << 4));
          *(uint4*)(baseo + g * 8) = v;
        }
      }
    }
  }
}

// ---------------- causal depthwise conv4 + bias + SiLU; emits xT, B, BT, C ----------------
// Fast path (cht < 64, x channels only): vectorized 16B input staging into a
// 132B-stride LDS tile (33-bank stride -> scalar reads are 2-way aliased = free),
// compute in transposed order (lr = lane, cc wave-uniform -> w/bias broadcast),
// store straight from registers to xT (out16 round-trip + barrier eliminated).
// Legacy path (cht 64/65: B needs dual layout, C row-major) byte-identical.
__global__ __launch_bounds__(256) void k_conv(const bfu* __restrict__ xbc, const float* __restrict__ cw,
    const float* __restrict__ cb, bfu* __restrict__ xT,
    bfu* __restrict__ B16o, bfu* __restrict__ BTo, bfu* __restrict__ C16o){
  int cht = blockIdx.x;                 // 0..65 channel tile (over CONV_DIM)
  int lt = blockIdx.y;                  // 0..127 seq tile over b*l
  int b = lt >> 6;
  int l0 = (lt & 63) << 6;
  int t = threadIdx.x;
  __shared__ float w[256];
  __shared__ float bias[64];
  __shared__ bfu in16[67][66];
  __shared__ bfu out16[64][66];
  __shared__ char in16p[67 * 132];      // fast-path input tile, 132B row stride
  if (t < 64) bias[t] = cb[cht * 64 + t];
  w[t] = cw[cht * 256 + t];
  int chbase = cht * 64;
  if (cht < 64){
    // ---- fast path: x channels only ----
    for (int i = t; i < 536; i += 256){
      int row = i >> 3, g = i & 7;
      int l = l0 + row - 3;
      uint4 v = {0u, 0u, 0u, 0u};
      if (l >= 0) v = *(const uint4*)(xbc + ((size_t)b * kSEQ + l) * kXBC + chbase + g * 8);
      unsigned* dst = (unsigned*)(in16p + row * 132 + g * 16);
      dst[0] = v.x; dst[1] = v.y; dst[2] = v.z; dst[3] = v.w;
    }
    __syncthreads();
    int lr = t & 63, ccb = t >> 6;
    size_t xTbase = ((size_t)b * kNH) * kHD * kSEQ;
    #pragma unroll
    for (int k = 0; k < 16; ++k){
      int cc = k * 4 + ccb;
      float acc = bias[cc];
      #pragma unroll
      for (int j = 0; j < 4; ++j)
        acc += bf2f(*(const bfu*)(in16p + (lr + j) * 132 + cc * 2)) * w[cc * 4 + j];
      float sv = acc / (1.f + __expf(-acc));
      int ch = chbase + cc;
      xT[xTbase + ((size_t)(ch >> 7) * kHD + (ch & 127)) * kSEQ + l0 + lr] = f2bf(sv);
    }
    return;
  }
  // ---- legacy path: B (dual layout) and C (row-major) ----
  for (int i = t; i < 67 * 64; i += 256){
    int rrow = i >> 6, cc = i & 63;
    int l = l0 + rrow - 3;
    bfu hv = 0;
    if (l >= 0) hv = xbc[((size_t)b * kSEQ + l) * kXBC + chbase + cc];
    in16[rrow][cc] = hv;
  }
  __syncthreads();
  for (int i = t; i < 4096; i += 256){
    int lr = i >> 6, cc = i & 63;
    float acc = bias[cc];
    #pragma unroll
    for (int j = 0; j < 4; ++j)
      acc += bf2f(in16[lr + j][cc]) * w[cc * 4 + j];
    float sv = acc / (1.f + __expf(-acc));
    out16[lr][cc] = f2bf(sv);
  }
  __syncthreads();
  // row-major outputs: B and C
  for (int i = t; i < 4096; i += 256){
    int lr = i >> 6, cc = i & 63;
    size_t row = (size_t)b * kSEQ + l0 + lr;
    int ch = chbase + cc;
    bfu v = out16[lr][cc];
    if (ch < 4096 + kDS) B16o[row * kDS + (ch - 4096)] = v;
    else                 C16o[row * kDS + (ch - 4096 - kDS)] = v;
  }
  // transposed output: B -> BT
  if (chbase < 4096 + kDS){
    for (int i = t; i < 4096; i += 256){
      int cc = i >> 6, lr = i & 63;
      int ch = chbase + cc;
      int lg = l0 + lr;
      bfu v = out16[lr][cc];
      if (ch < 4096 + kDS)
        BTo[((size_t)b * kDS + (ch - 4096)) * kSEQ + lg] = v;
    }
  }
}

// ---------------- dt = softplus(raw + bias); dA = -exp(A_log)*dt; per-chunk inclusive cumsum ----------------
__global__ __launch_bounds__(256) void k_dtscan(const bfu* __restrict__ xbc, const float* __restrict__ dt_bias,
    const float* __restrict__ A_log, float* __restrict__ dtf, float* __restrict__ acum){
  int bi = blockIdx.x;                  // ((b*16+c)*32+h)
  int h = bi & 31, c = (bi >> 5) & 15, b = bi >> 9;
  int t = threadIdx.x;
  size_t row = (size_t)b * kSEQ + c * kCH + t;
  float draw = bf2f(xbc[row * kXBC + kCV + h]) + dt_bias[h];
  float dt = (draw > 20.f) ? draw : log1pf(__expf(draw));
  dtf[row * kNH + h] = dt;
  float dA = -__expf(A_log[h]) * dt;
  __shared__ float s[256];
  s[t] = dA;
  __syncthreads();
  #pragma unroll
  for (int off = 1; off < 256; off <<= 1){
    float v = (t >= off) ? s[t - off] : 0.f;
    __syncthreads();
    s[t] += v;
    __syncthreads();
  }
  acum[(size_t)bi * 256 + t] = s[t];
}

// ---------------- per-chunk local states[p][n] = sum_l Xt[p][l] * B[l][n]*dt[l]*exp(Atot-Acum[l]) ----------------
__global__ __launch_bounds__(256) void k_states(const bfu* __restrict__ xT, const bfu* __restrict__ BT,
    const float* __restrict__ dtf, const float* __restrict__ acum, bfu* __restrict__ states){
  int bi = blockIdx.x;
  int h = bi & 31, c = (bi >> 5) & 15, b = bi >> 9;
  int t = threadIdx.x, lane = t & 63, wave = t >> 6;
  int wr = wave >> 1, wc = wave & 1;
  __shared__ uint4 ldsX4[1024];         // [128 p][64 l] bf16
  __shared__ uint4 ldsB4[512];          // [64 n][64 l] bf16 (scaled)
  __shared__ float dsv[256];
  char* ldsX = (char*)ldsX4;
  char* ldsB = (char*)ldsB4;
  float Atot = acum[(size_t)bi * 256 + 255];
  {
    size_t row = (size_t)b * kSEQ + c * kCH + t;
    dsv[t] = dtf[row * kNH + h] * __expf(Atot - acum[(size_t)bi * 256 + t]);
  }
  f4v zz = {0.f, 0.f, 0.f, 0.f};
  f4v acc[4][2];
  #pragma unroll
  for (int m = 0; m < 4; ++m){ acc[m][0] = zz; acc[m][1] = zz; }
  const bfu* xTp = xT + ((size_t)b * kNH + h) * kHD * kSEQ + c * kCH;
  const bfu* BTp = BT + (size_t)b * kDS * kSEQ + c * kCH;
  __syncthreads();
  for (int kb = 0; kb < 4; ++kb){
    #pragma unroll
    for (int it = 0; it < 4; ++it){
      int s = it * 256 + t;
      int row = s >> 3;
      int srcslot = (s & 7) ^ (row & 7);
      gld_lds16(xTp + (size_t)row * kSEQ + kb * 64 + srcslot * 8,
                ldsX + it * 4096 + wave * 1024, lane);
    }
    #pragma unroll
    for (int it = 0; it < 2; ++it){
      int cidx = it * 256 + t;
      int row = cidx >> 3, slot = cidx & 7;
      uint4 v = *(const uint4*)(BTp + (size_t)row * kSEQ + kb * 64 + slot * 8);
      bfu* hp = (bfu*)&v;
      #pragma unroll
      for (int j = 0; j < 8; ++j)
        hp[j] = f2bf(bf2f(hp[j]) * dsv[kb * 64 + slot * 8 + j]);
      *(uint4*)(ldsB + (((row << 3) + (slot ^ (row & 7))) << 4)) = v;
    }
    __syncthreads();
    s8v af[4][2], bb[2][2];
    #pragma unroll
    for (int m = 0; m < 4; ++m){
      af[m][0] = frag_ld(ldsX, wr * 64 + m * 16, 0, lane);
      af[m][1] = frag_ld(ldsX, wr * 64 + m * 16, 1, lane);
    }
    #pragma unroll
    for (int nf = 0; nf < 2; ++nf){
      bb[nf][0] = frag_ld(ldsB, wc * 32 + nf * 16, 0, lane);
      bb[nf][1] = frag_ld(ldsB, wc * 32 + nf * 16, 1, lane);
    }
    #pragma unroll
    for (int kh = 0; kh < 2; ++kh)
      #pragma unroll
      for (int m = 0; m < 4; ++m)
        #pragma unroll
        for (int nf = 0; nf < 2; ++nf)
          acc[m][nf] = MFMA16(af[m][kh], bb[nf][kh], acc[m][nf], 0, 0, 0);
    __syncthreads();
  }
  bfu* sp = states + (size_t)bi * 8192;
  int r0 = (lane >> 4) << 2;
  #pragma unroll
  for (int m = 0; m < 4; ++m)
    #pragma unroll
    for (int nf = 0; nf < 2; ++nf)
      #pragma unroll
      for (int r = 0; r < 4; ++r){
        int p = wr * 64 + m * 16 + r0 + r;
        int n = wc * 32 + nf * 16 + (lane & 15);
        sp[p * 64 + n] = f2bf(acc[m][nf][r]);
      }
}

// ---------------- inter-chunk state recurrence (in-place; split over 4 j-groups) ----------------
__global__ __launch_bounds__(256) void k_scan(bfu* __restrict__ st, const float* __restrict__ acum){
  int bh = blockIdx.x >> 2;             // 0..63  (b*32+h)
  int jg = blockIdx.x & 3;              // 0..3
  int b = bh >> 5, h = bh & 31;
  int t = threadIdx.x;
  float run[8];
  #pragma unroll
  for (int j = 0; j < 8; ++j) run[j] = 0.f;
  for (int c = 0; c < 16; ++c){
    size_t bi = (size_t)((b * 16 + c) * 32 + h);
    float eT = __expf(acum[bi * 256 + 255]);
    size_t base = bi * 8192 + (size_t)jg * 2048;
    #pragma unroll
    for (int j = 0; j < 8; ++j){
      size_t idx = base + j * 256 + t;
      float sl = bf2f(st[idx]);
      st[idx] = f2bf(run[j]);
      run[j] = run[j] * eT + sl;
    }
  }
}

// ---------------- Y = (P + D*I)X + Y_off, * silu(z) -> y16; merged p-halves + ssq partials ----------------
__global__ __launch_bounds__(512, 2) void k_y(
    const bfu* __restrict__ xT, const bfu* __restrict__ Bm, const bfu* __restrict__ Cm,
    const bfu* __restrict__ SIs, const float* __restrict__ dtf, const float* __restrict__ acum,
    const bfu* __restrict__ z16, const float* __restrict__ Dp,
    bfu* __restrict__ y16, float* __restrict__ ssq)
{
  int bi = blockIdx.x;
  int h = bi & 31, c = (bi >> 5) & 15, b = bi >> 9;
  int t = threadIdx.x, lane = t & 63, wave = t >> 6;
  int rw = wave & 3;                    // PV row-group (64 rows)
  int pg = wave >> 2;                   // p-half (64 cols of head dim)
  int tl = rw * 64 + lane;              // thread index within pg-group (0..255)
  __shared__ uint4 ldsP4[2048];         // P [256][64] bf16 = 32KB (swizzled); reused as Y restage
  __shared__ uint4 ldsT4[1024];         // per-pg [64][64] bf16 tile (SI then X), 2 x 8KB
  __shared__ float acumS[256];
  __shared__ float dtS[256];
  char* ldsP = (char*)ldsP4;
  char* ldsT = ((char*)ldsT4) + pg * 8192;
  size_t rowbase = (size_t)b * kSEQ + c * kCH;
  if (t < 256){
    acumS[t] = acum[(size_t)bi * 256 + t];
    dtS[t] = dtf[(rowbase + t) * kNH + h];
  }
  // stage SI tile for this pg (4 waves x 2KB, swizzled direct write)
  const bfu* SIp = SIs + (size_t)bi * 8192 + (size_t)pg * 4096;  // [64 p][64 n] bf16
  #pragma unroll
  for (int it = 0; it < 2; ++it){
    int cidx = it * 256 + tl;
    int row = cidx >> 3, slot = cidx & 7;
    uint4 v = *(const uint4*)(SIp + row * 64 + slot * 8);
    *(uint4*)(ldsT + (((row << 3) + (slot ^ (row & 7))) << 4)) = v;
  }
  const bfu* Cp = Cm + rowbase * kDS;
  s8v cfP[4][2];                        // C-frags for PV/acc-init rows rw*64..
  #pragma unroll
  for (int m = 0; m < 4; ++m){
    cfP[m][0] = *(const s8v*)(Cp + (size_t)(rw * 64 + m * 16 + (lane & 15)) * kDS + ((lane >> 4) << 3));
    cfP[m][1] = *(const s8v*)(Cp + (size_t)(rw * 64 + m * 16 + (lane & 15)) * kDS + 32 + ((lane >> 4) << 3));
  }
  s8v cfS[2][2];                        // C-frags for sv rows wave*32..
  #pragma unroll
  for (int m = 0; m < 2; ++m){
    cfS[m][0] = *(const s8v*)(Cp + (size_t)(wave * 32 + m * 16 + (lane & 15)) * kDS + ((lane >> 4) << 3));
    cfS[m][1] = *(const s8v*)(Cp + (size_t)(wave * 32 + m * 16 + (lane & 15)) * kDS + 32 + ((lane >> 4) << 3));
  }
  __syncthreads();
  float ArowP[16];
  #pragma unroll
  for (int m = 0; m < 4; ++m)
    #pragma unroll
    for (int r = 0; r < 4; ++r)
      ArowP[m * 4 + r] = acumS[rw * 64 + m * 16 + ((lane >> 4) << 2) + r];
  float ArowS[8];
  #pragma unroll
  for (int m = 0; m < 2; ++m)
    #pragma unroll
    for (int r = 0; r < 4; ++r)
      ArowS[m * 4 + r] = acumS[wave * 32 + m * 16 + ((lane >> 4) << 2) + r];
  f4v acc[4][4];
  {
    s8v bfo[4][2];
    #pragma unroll
    for (int pf = 0; pf < 4; ++pf){
      bfo[pf][0] = frag_ld(ldsT, pf << 4, 0, lane);
      bfo[pf][1] = frag_ld(ldsT, pf << 4, 1, lane);
    }
    f4v zz = {0.f, 0.f, 0.f, 0.f};
    #pragma unroll
    for (int m = 0; m < 4; ++m)
      #pragma unroll
      for (int pf = 0; pf < 4; ++pf){
        f4v v = zz;
        v = MFMA16(cfP[m][0], bfo[pf][0], v, 0, 0, 0);
        v = MFMA16(cfP[m][1], bfo[pf][1], v, 0, 0, 0);
        #pragma unroll
        for (int r = 0; r < 4; ++r) v[r] *= __expf(ArowP[m * 4 + r]);
        acc[m][pf] = v;
      }
  }
  float Dh = Dp[h];
  const bfu* Bp = Bm + rowbase * kDS;
  const bfu* xTp = xT + (((size_t)b * kNH + h) * kHD + pg * 64) * kSEQ + c * kCH;
  #pragma unroll 1
  for (int sb = 0; sb < 4; ++sb){
    __syncthreads();                    // prev PV reads of ldsT/ldsP done
    #pragma unroll
    for (int it = 0; it < 2; ++it){
      int s = it * 256 + tl;
      int row = s >> 3;
      int srcslot = (s & 7) ^ (row & 7);
      gld_lds16(xTp + (size_t)row * kSEQ + sb * 64 + srcslot * 8,
                ldsT + it * 4096 + rw * 1024, lane);
    }
    f4v sv[2][4];
    {
      s8v bsf[4][2];
      #pragma unroll
      for (int sf = 0; sf < 4; ++sf){
        bsf[sf][0] = *(const s8v*)(Bp + (size_t)(sb * 64 + sf * 16 + (lane & 15)) * kDS + ((lane >> 4) << 3));
        bsf[sf][1] = *(const s8v*)(Bp + (size_t)(sb * 64 + sf * 16 + (lane & 15)) * kDS + 32 + ((lane >> 4) << 3));
      }
      f4v zz = {0.f, 0.f, 0.f, 0.f};
      #pragma unroll
      for (int m = 0; m < 2; ++m)
        #pragma unroll
        for (int sf = 0; sf < 4; ++sf){
          f4v v = zz;
          v = MFMA16(cfS[m][0], bsf[sf][0], v, 0, 0, 0);
          v = MFMA16(cfS[m][1], bsf[sf][1], v, 0, 0, 0);
          sv[m][sf] = v;
        }
    }
    int scb = sb << 6;
    float As[4], dts_[4];
    #pragma unroll
    for (int sf = 0; sf < 4; ++sf){
      As[sf] = acumS[scb + sf * 16 + (lane & 15)];
      dts_[sf] = dtS[scb + sf * 16 + (lane & 15)];
    }
    #pragma unroll
    for (int m = 0; m < 2; ++m)
      #pragma unroll
      for (int sf = 0; sf < 4; ++sf)
        #pragma unroll
        for (int r = 0; r < 4; ++r){
          int pr = wave * 32 + m * 16 + ((lane >> 4) << 2) + r;   // P row 0..255
          int scl = sf * 16 + (lane & 15);
          int d = pr - (scb + scl);
          float pv = 0.f;
          if (d >= 0)
            pv = sv[m][sf][r] * __expf(ArowS[m * 4 + r] - As[sf]) * dts_[sf];
          if (d == 0)
            pv += Dh;                   // D-skip folded into P diagonal
          *(bfu*)(ldsP + pr * 128 + ((((scl >> 3) ^ (pr & 7)) << 3) + (scl & 7)) * 2) = f2bf(pv);
        }
    __syncthreads();                    // P ready + X staged (vmcnt drained)
    s8v xb[4][2];
    #pragma unroll
    for (int pf = 0; pf < 4; ++pf){
      xb[pf][0] = frag_ld(ldsT, pf << 4, 0, lane);
      xb[pf][1] = frag_ld(ldsT, pf << 4, 1, lane);
    }
    #pragma unroll
    for (int m = 0; m < 4; ++m){
      s8v pa0 = frag_ld(ldsP, rw * 64 + m * 16, 0, lane);
      s8v pa1 = frag_ld(ldsP, rw * 64 + m * 16, 1, lane);
      #pragma unroll
      for (int pf = 0; pf < 4; ++pf){
        acc[m][pf] = MFMA16(pa0, xb[pf][0], acc[m][pf], 0, 0, 0);
        acc[m][pf] = MFMA16(pa1, xb[pf][1], acc[m][pf], 0, 0, 0);
      }
    }
  }
  // ---- coalesced gated epilogue: two col-halves through ldsP; ssq partials ----
  char* ldsY = (char*)ldsP4;
  float myss[4] = {0.f, 0.f, 0.f, 0.f};
  #pragma unroll
  for (int half = 0; half < 2; ++half){
    __syncthreads();
    if (pg == half){
      #pragma unroll
      for (int m = 0; m < 4; ++m)
        #pragma unroll
        for (int pf = 0; pf < 4; ++pf)
          #pragma unroll
          for (int r = 0; r < 4; ++r){
            int rloc = rw * 64 + m * 16 + ((lane >> 4) << 2) + r;
            int col  = (pf << 4) + (lane & 15);
            *(bfu*)(ldsY + rloc * 128 + (((col >> 3) ^ (rloc & 7)) << 4) + (col & 7) * 2) = f2bf(acc[m][pf][r]);
          }
    }
    __syncthreads();
    int cg0 = (h << 7) + (half << 6);
    #pragma unroll
    for (int j = 0; j < 4; ++j){
      int idx = j * 512 + t;            // 0..2047
      int row = idx >> 3, g = idx & 7;
      uint4 yv = *(const uint4*)(ldsY + row * 128 + ((g ^ (row & 7)) << 4));
      size_t rowg = rowbase + row;
      uint4 zv4 = *(const uint4*)(z16 + rowg * kDI + cg0 + g * 8);
      const bfu* yp = (const bfu*)&yv;
      const bfu* zp = (const bfu*)&zv4;
      uint4 outv; bfu* op = (bfu*)&outv;
      float ls = 0.f;
      #pragma unroll
      for (int e = 0; e < 8; ++e){
        float zv = bf2f(zp[e]);
        float sg = zv / (1.f + __expf(-zv));
        op[e] = f2bf(bf2f(yp[e]) * sg);
        float gv = bf2f(op[e]);
        ls += gv * gv;
      }
      myss[j] += ls;
      *(uint4*)(y16 + rowg * kLDY + cg0 + g * 8) = outv;
    }
  }
  // reduce 8 lanes per row (t&7 groups share a row), one partial per (row, head)
  #pragma unroll
  for (int j = 0; j < 4; ++j){
    float red = myss[j];
    red += __shfl_down(red, 4, 8);
    red += __shfl_down(red, 2, 8);
    red += __shfl_down(red, 1, 8);
    if ((t & 7) == 0){
      int row = j * 64 + (t >> 3);
      ssq[(rowbase + row) * kNH + h] = red;
    }
  }
}

extern "C" void kernel_launch(void* const* d_in, const int* in_sizes, int n_in,
                              void* d_out, int out_size, void* d_ws, size_t ws_size,
                              hipStream_t stream){
  (void)in_sizes; (void)n_in; (void)out_size; (void)ws_size;
  const float* u       = (const float*)d_in[0];
  const float* W_in    = (const float*)d_in[1];
  const float* conv_w  = (const float*)d_in[2];
  const float* conv_b  = (const float*)d_in[3];
  const float* dt_bias = (const float*)d_in[4];
  const float* A_log   = (const float*)d_in[5];
  const float* Dp      = (const float*)d_in[6];
  const float* norm_w  = (const float*)d_in[7];
  const float* W_out   = (const float*)d_in[8];
  char* ws = (char*)d_ws;

  // Workspace layout: ~243.8 MB total, with lifetime overlays.
  const size_t o_z    = 0;                                     // z16 [8192][4096] bf16   67.11 MB
  const size_t o_xbc  = o_z   + (size_t)kBL * kDI * 2;         // xbc [8192][4256] bf16 -> y16 [8192][4160] after conv
  const size_t o_u16  = o_xbc + (size_t)kBL * kXBC * 2;        // u16 -> states + woutT
  const size_t o_xT   = o_u16 + (size_t)kBL * kDM * 2;         // xT slot (winT lives here until GEMM1 ends)
  const size_t o_B16  = o_xT  + (size_t)kBL * kDI * 2;
  const size_t o_BT   = o_B16 + (size_t)kBL * kDS * 2;
  const size_t o_C16  = o_BT  + (size_t)kBL * kDS * 2;
  const size_t o_dtf  = o_C16 + (size_t)kBL * kDS * 2;
  const size_t o_acum = o_dtf + (size_t)kBL * kNH * 4;
  const size_t o_ssq  = o_acum + (size_t)1024 * 256 * 4;       // ssq [8192][32] f32, 1 MB
  // overlays:
  const size_t o_states = o_u16;                               // after GEMM1
  const size_t o_woutT  = o_u16 + (size_t)1024 * 8192 * 2;     // after GEMM1
  const size_t o_winT   = o_xT;                                // before conv
  const size_t o_y16    = o_xbc;                               // after conv+dtscan

  bfu* z16    = (bfu*)(ws + o_z);
  bfu* xbc    = (bfu*)(ws + o_xbc);
  bfu* u16    = (bfu*)(ws + o_u16);
  bfu* xT     = (bfu*)(ws + o_xT);
  bfu* B16    = (bfu*)(ws + o_B16);
  bfu* BT     = (bfu*)(ws + o_BT);
  bfu* C16    = (bfu*)(ws + o_C16);
  float* dtf  = (float*)(ws + o_dtf);
  float* acum = (float*)(ws + o_acum);
  float* ssq  = (float*)(ws + o_ssq);
  bfu* statesS= (bfu*)(ws + o_states);
  bfu* woutT  = (bfu*)(ws + o_woutT);
  bfu* winT   = (bfu*)(ws + o_winT);
  bfu* y16    = (bfu*)(ws + o_y16);

  // allow 72 KiB dynamic LDS on the big GEMMs (idempotent, capture-safe)
  (void)hipFuncSetAttribute(reinterpret_cast<const void*>(&k_gemm256<2>),
                            hipFuncAttributeMaxDynamicSharedMemorySize, 73728);
  (void)hipFuncSetAttribute(reinterpret_cast<const void*>(&k_gemm256<0>),
                            hipFuncAttributeMaxDynamicSharedMemorySize, 73728);

  // zero the 96 pad rows of winT (rows kDP..kDPpad, width kLDW)
  k_zero<<<(96 * kLDW + 255) / 256, 256, 0, stream>>>(winT + (size_t)kDP * kLDW, 96 * kLDW);
  k_cvt<<<2048, 256, 0, stream>>>(u, u16, kBL * kDM / 8);
  k_transpose<<<dim3(kDP / 32, kDM / 32), dim3(32, 8), 0, stream>>>(W_in, winT, kDM, kDP, nullptr, kLDW);
  k_gemm256<2><<<(kDPpad / 128) * (kBL / 256), 512, 73728, stream>>>(u16, winT, nullptr, z16, xbc, nullptr, kDPpad / 128, kDPpad, kDM, kDM, kLDW);
  k_conv<<<dim3(kCV / 64, kBL / 64), 256, 0, stream>>>(xbc, conv_w, conv_b, xT, B16, BT, C16);
  k_dtscan<<<1024, 256, 0, stream>>>(xbc, dt_bias, A_log, dtf, acum);
  // woutT[n][k] = W_out[k][n] * norm_w[k]  (norm weight folded into weights)
  k_transpose<<<dim3(kDM / 32, kDI / 32), dim3(32, 8), 0, stream>>>(W_out, woutT, kDI, kDM, norm_w, kDI);
  k_states<<<1024, 256, 0, stream>>>(xT, BT, dtf, acum, statesS);
  k_scan<<<256, 256, 0, stream>>>(statesS, acum);
  k_y<<<1024, 512, 0, stream>>>(xT, B16, C16, statesS, dtf, acum, z16, Dp, y16, ssq);
  k_gemm256<0><<<(kDM / 128) * (kBL / 256), 512, 73728, stream>>>(y16, woutT, (float*)d_out, nullptr, nullptr, ssq, kDM / 128, kDM, kDI, kLDY, kDI);
}